// Round 13
// baseline (2667.451 us; speedup 1.0000x reference)
//
#include <hip/hip_runtime.h>

typedef __attribute__((ext_vector_type(8))) short short8;
typedef __attribute__((ext_vector_type(4))) float f32x4;
typedef __attribute__((ext_vector_type(4))) unsigned int u32x4;

#define DEV static __device__ __forceinline__

DEV unsigned short f2bf(float f){
  unsigned int u = __float_as_uint(f);
  u += 0x7FFFu + ((u >> 16) & 1u);
  return (unsigned short)(u >> 16);
}
DEV float bf2f(unsigned short h){ return __uint_as_float(((unsigned int)h) << 16); }

DEV f32x4 ntload4(const float* p){ return __builtin_nontemporal_load((const f32x4*)p); }
DEV void ntstore4(float* p, f32x4 v){ __builtin_nontemporal_store(v, (f32x4*)p); }

#define DTM 0.1f   /* DT*TAU_MEM_INV */
#define SYN 0.8f   /* 1 - DT*TAU_SYN_INV */
#define VTH 0.2f

// ---------------------------------------------------------------------------
// prep: weights -> MFMA-fragment-major bf16 hi/mid/lo digit layout (as r12).
// ---------------------------------------------------------------------------
__global__ __launch_bounds__(256) void prep_kernel(
    const float* __restrict__ w2, const float* __restrict__ w3, const float* __restrict__ w4,
    unsigned short* __restrict__ wb2h, unsigned short* __restrict__ wb2m, unsigned short* __restrict__ wb2l,
    unsigned short* __restrict__ wb3h, unsigned short* __restrict__ wb3m, unsigned short* __restrict__ wb3l,
    unsigned short* __restrict__ wb4h, unsigned short* __restrict__ wb4m, unsigned short* __restrict__ wb4l)
{
  const int N2 = 9*128*64, N3 = 9*256*128, N4 = 9*256*256;
  int tid = blockIdx.x*256 + threadIdx.x;
  if (tid < N2) {
    int j = tid & 7, co = (tid >> 3) & 127, q = (tid >> 3) >> 7;
    int kg = q & 3, sg = q >> 2;
    int tap = sg >> 1, ks = sg & 1;
    int ci = ks*32 + kg*8 + j;
    float w = w2[(co*64 + ci)*9 + tap];
    unsigned short h = f2bf(w);   float r1 = w - bf2f(h);
    unsigned short m = f2bf(r1);  float r2 = r1 - bf2f(m);
    wb2h[tid] = h; wb2m[tid] = m; wb2l[tid] = f2bf(r2);
    return;
  }
  tid -= N2;
  if (tid < N3) {
    int j = tid & 7, co = (tid >> 3) & 255, q = (tid >> 3) >> 8;
    int kg = q & 3, sg = q >> 2;
    int p = sg >> 1, ks = sg & 1, tap = p >> 1, cs = p & 1;
    int ci = cs*64 + ks*32 + kg*8 + j;
    float w = w3[(co*128 + ci)*9 + tap];
    unsigned short h = f2bf(w);   float r1 = w - bf2f(h);
    unsigned short m = f2bf(r1);  float r2 = r1 - bf2f(m);
    wb3h[tid] = h; wb3m[tid] = m; wb3l[tid] = f2bf(r2);
    return;
  }
  tid -= N3;
  if (tid < N4) {
    int j = tid & 7, co = (tid >> 3) & 255, q = (tid >> 3) >> 8;
    int kg = q & 3, sg = q >> 2;
    int hh = sg / 36, sl = sg % 36;
    int p = sl >> 1, ks = sl & 1, tap = p >> 1, cs = p & 1;
    int ci = hh*128 + cs*64 + ks*32 + kg*8 + j;
    float w = w4[(co*256 + ci)*9 + tap];
    unsigned short h = f2bf(w);   float r1 = w - bf2f(h);
    unsigned short m = f2bf(r1);  float r2 = r1 - bf2f(m);
    wb4h[tid] = h; wb4m[tid] = m; wb4l[tid] = f2bf(r2);
  }
}

// ---------------------------------------------------------------------------
// k1 body: conv1 (fp32 direct, 3->64) + LIF1. 512 blocks x 256 thr.
// ---------------------------------------------------------------------------
DEV void k1_body(char* smem, int bid,
    const float* __restrict__ x, const float* __restrict__ w1,
    float* __restrict__ v1, float* __restrict__ i1,
    unsigned short* __restrict__ z1, int t)
{
  float* xs = (float*)smem;            // [3][4][34]
  float* wl = xs + 3*4*34;             // [27][64]
  int tid = threadIdx.x;
  int b = bid >> 4, y0 = (bid & 15) * 2;
  for (int e = tid; e < 3*4*34; e += 256) {
    int ci = e/136, r2 = e%136, r = r2/34, xi = r2%34;
    int y = y0 - 1 + r, xg = xi - 1;
    float v = 0.f;
    if (y >= 0 && y < 32 && xg >= 0 && xg < 32)
      v = x[((t*32 + b)*3 + ci)*1024 + y*32 + xg];
    xs[ci*136 + r*34 + xi] = v;
  }
  for (int e = tid; e < 27*64; e += 256) {
    int row = e >> 6, co = e & 63;
    int ci = row % 3, tap = row / 3, ky = tap/3, kx = tap%3;
    wl[row*64 + co] = w1[((co*3+ci)*3+ky)*3+kx];
  }
  __syncthreads();
  int px = tid >> 2, cg = tid & 3;
  int ly = px >> 5, lx = px & 31;
  float acc[16];
#pragma unroll
  for (int q = 0; q < 16; q++) acc[q] = 0.f;
#pragma unroll
  for (int ky = 0; ky < 3; ky++)
#pragma unroll
    for (int kx = 0; kx < 3; kx++)
#pragma unroll
      for (int ci = 0; ci < 3; ci++) {
        float xv = xs[ci*136 + (ly+ky)*34 + (lx+kx)];
        const float4* wr = (const float4*)&wl[((ky*3+kx)*3+ci)*64 + cg*16];
#pragma unroll
        for (int q = 0; q < 4; q++) {
          float4 w4 = wr[q];
          acc[q*4+0] = fmaf(xv, w4.x, acc[q*4+0]);
          acc[q*4+1] = fmaf(xv, w4.y, acc[q*4+1]);
          acc[q*4+2] = fmaf(xv, w4.z, acc[q*4+2]);
          acc[q*4+3] = fmaf(xv, w4.w, acc[q*4+3]);
        }
      }
  int m_g = b*1024 + (y0+ly)*32 + lx;
  unsigned short zb[16];
#pragma unroll
  for (int q = 0; q < 4; q++) {
    int idx = m_g*64 + cg*16 + q*4;
    float vv[4] = {0.f,0.f,0.f,0.f}, ii[4] = {0.f,0.f,0.f,0.f};
    if (t != 0) {
      float4 v4 = *(const float4*)(v1+idx); float4 i4 = *(const float4*)(i1+idx);
      vv[0]=v4.x; vv[1]=v4.y; vv[2]=v4.z; vv[3]=v4.w;
      ii[0]=i4.x; ii[1]=i4.y; ii[2]=i4.z; ii[3]=i4.w;
    }
#pragma unroll
    for (int s = 0; s < 4; s++) {
      float vdec = vv[s] + DTM*((0.0f - vv[s]) + ii[s]);
      bool z = (vdec - VTH) > 0.0f;
      vv[s] = z ? 0.0f : vdec;
      ii[s] = SYN*ii[s] + acc[q*4+s];
      zb[q*4+s] = z ? 0x3F80 : 0;
    }
    *(float4*)(v1+idx) = make_float4(vv[0],vv[1],vv[2],vv[3]);
    *(float4*)(i1+idx) = make_float4(ii[0],ii[1],ii[2],ii[3]);
  }
  u32x4 za, zc;
  za[0]=zb[0]|((unsigned)zb[1]<<16); za[1]=zb[2]|((unsigned)zb[3]<<16);
  za[2]=zb[4]|((unsigned)zb[5]<<16); za[3]=zb[6]|((unsigned)zb[7]<<16);
  zc[0]=zb[8]|((unsigned)zb[9]<<16); zc[1]=zb[10]|((unsigned)zb[11]<<16);
  zc[2]=zb[12]|((unsigned)zb[13]<<16); zc[3]=zb[14]|((unsigned)zb[15]<<16);
  *(u32x4*)(z1 + m_g*64 + cg*16) = za;
  *(u32x4*)(z1 + m_g*64 + cg*16 + 8) = zc;
}

// ---------------------------------------------------------------------------
// conv body (r12 conv_lif verbatim, smem/bid passed in).
// ---------------------------------------------------------------------------
template<int MF, int CIN_A, int WI, int HIM, int COUT, int CIN_SRC,
         int NT, bool KSPLIT, bool POOLZ>
DEV void conv_body(char* smem, int bid,
    const unsigned short* __restrict__ zsrc,
    const unsigned short* __restrict__ wbh, const unsigned short* __restrict__ wbm,
    const unsigned short* __restrict__ wbl,
    float* __restrict__ vst, float* __restrict__ ist,
    unsigned short* __restrict__ zpool,
    float* __restrict__ part0, float* __restrict__ part1, int t)
{
  constexpr int THREADS = 256;
  constexpr int BM = MF*16;
  constexpr int BN = 64;
  constexpr int ROWS = BM/WI;
  constexpr int SLOTW = WI+2;
  constexpr int SLOTS = (ROWS+2)*SLOTW;
  constexpr int CPH = CIN_A/64;
  constexpr int NSC = 9*CPH;
  constexpr int MT_PER_B = (HIM*WI)/BM;
  constexpr int ACH = CIN_A/8;
  constexpr int ACHUNKS = SLOTS*ACH;
  constexpr int GSTRIDE = (SLOTS+1)*16;
  constexpr int ABYTES = ACH*GSTRIDE;
  constexpr int CBYTES = BM*BN*4;
  constexpr int ZBYTES = POOLZ ? BM*BN*2 : 0;
  constexpr int EBYTES = CBYTES + ZBYTES;
  constexpr int LDSB = ABYTES > EBYTES ? ABYTES : EBYTES;
  static_assert(LDSB <= 24576, "LDS");

  int tid = threadIdx.x;
  int rem = bid;
  int kh = 0;
  if constexpr (KSPLIT) { kh = rem & 1; rem >>= 1; }
  int nt = 0;
  if constexpr (NT > 1) { nt = rem % NT; rem /= NT; }
  int b = rem / MT_PER_B;
  int y0 = (rem % MT_PER_B) * ROWS;
  int lane = tid & 63, wn = tid >> 6;
  int kg = lane >> 4;
  int csrc0 = KSPLIT ? kh*CIN_A : 0;

  for (int ch = tid; ch < ACHUNKS; ch += THREADS) {
    int slot = ch / ACH, g = ch % ACH;
    int yr = slot / SLOTW, xr = slot % SLOTW;
    int y = y0 + yr - 1, xg = xr - 1;
    u32x4 val; val[0]=0; val[1]=0; val[2]=0; val[3]=0;
    if (y >= 0 && y < HIM && xg >= 0 && xg < WI)
      val = *(const u32x4*)(zsrc + ((long)(b*HIM + y)*WI + xg)*CIN_SRC + csrc0 + g*8);
    *(u32x4*)(smem + g*GSTRIDE + slot*16) = val;
  }

  int abase[MF];
#pragma unroll
  for (int mf = 0; mf < MF; mf++) {
    int pl = mf*16 + (lane & 15);
    int yl = pl / WI, xl = pl % WI;
    abase[mf] = kg*GSTRIDE + (yl*SLOTW + xl)*16;
  }

  int co_g = nt*BN + wn*16 + (lane & 15);
  const long bstep = (long)4*COUT*8;
  long bo = ((long)kg*COUT + co_g)*8 + (KSPLIT ? (long)(kh*NSC*2)*bstep : 0);

  f32x4 acc[MF];
#pragma unroll
  for (int mf = 0; mf < MF; mf++) {
    acc[mf][0]=0.f; acc[mf][1]=0.f; acc[mf][2]=0.f; acc[mf][3]=0.f;
  }

  short8 ch0 = *(const short8*)(wbh + bo);
  short8 cm0 = *(const short8*)(wbm + bo);
  short8 cl0 = *(const short8*)(wbl + bo);
  short8 ch1 = *(const short8*)(wbh + bo + bstep);
  short8 cm1 = *(const short8*)(wbm + bo + bstep);
  short8 cl1 = *(const short8*)(wbl + bo + bstep);

  __syncthreads();

#pragma unroll 1
  for (int sc = 0; sc < NSC; sc++) {
    long bon = bo + ((sc + 1 < NSC) ? 2*bstep : 0);
    short8 nh0 = *(const short8*)(wbh + bon);
    short8 nm0 = *(const short8*)(wbm + bon);
    short8 nl0 = *(const short8*)(wbl + bon);
    short8 nh1 = *(const short8*)(wbh + bon + bstep);
    short8 nm1 = *(const short8*)(wbm + bon + bstep);
    short8 nl1 = *(const short8*)(wbl + bon + bstep);

    int tap, cs;
    if constexpr (CPH == 1) { tap = sc; cs = 0; }
    else { tap = sc >> 1; cs = sc & 1; }
    int ty = (tap*171) >> 9;
    int tx = tap - ty*3;
    int base0 = (cs*8)*GSTRIDE + (ty*SLOTW + tx)*16;

    short8 a0[MF], a1[MF];
#pragma unroll
    for (int mf = 0; mf < MF; mf++)
      a0[mf] = *(const short8*)(smem + abase[mf] + base0);
#pragma unroll
    for (int mf = 0; mf < MF; mf++)
      a1[mf] = *(const short8*)(smem + abase[mf] + base0 + 4*GSTRIDE);

#pragma unroll
    for (int mf = 0; mf < MF; mf++)
      acc[mf] = __builtin_amdgcn_mfma_f32_16x16x32_bf16(a0[mf], ch0, acc[mf], 0, 0, 0);
#pragma unroll
    for (int mf = 0; mf < MF; mf++)
      acc[mf] = __builtin_amdgcn_mfma_f32_16x16x32_bf16(a0[mf], cm0, acc[mf], 0, 0, 0);
#pragma unroll
    for (int mf = 0; mf < MF; mf++)
      acc[mf] = __builtin_amdgcn_mfma_f32_16x16x32_bf16(a0[mf], cl0, acc[mf], 0, 0, 0);
#pragma unroll
    for (int mf = 0; mf < MF; mf++)
      acc[mf] = __builtin_amdgcn_mfma_f32_16x16x32_bf16(a1[mf], ch1, acc[mf], 0, 0, 0);
#pragma unroll
    for (int mf = 0; mf < MF; mf++)
      acc[mf] = __builtin_amdgcn_mfma_f32_16x16x32_bf16(a1[mf], cm1, acc[mf], 0, 0, 0);
#pragma unroll
    for (int mf = 0; mf < MF; mf++)
      acc[mf] = __builtin_amdgcn_mfma_f32_16x16x32_bf16(a1[mf], cl1, acc[mf], 0, 0, 0);

    ch0 = nh0; cm0 = nm0; cl0 = nl0;
    ch1 = nh1; cm1 = nm1; cl1 = nl1;
    bo = bon;
  }

  __syncthreads();
  float* cb = (float*)smem;
  unsigned short* zb = (unsigned short*)(smem + CBYTES);
  {
    int chn = wn*16 + (lane & 15);
#pragma unroll
    for (int mf = 0; mf < MF; mf++)
#pragma unroll
      for (int r = 0; r < 4; r++) {
        int pix = mf*16 + (lane >> 4)*4 + r;
        cb[pix*BN + (chn ^ ((pix & 3) << 4))] = acc[mf][r];
      }
  }
  __syncthreads();
  constexpr int ITER = (BM*BN/4)/THREADS;
  int mbase = (b*HIM + y0)*WI;
  float* pdst = KSPLIT ? (kh ? part1 : part0) : nullptr;
#pragma unroll
  for (int k = 0; k < ITER; k++) {
    int e = k*THREADS + tid;
    int row = e >> 4;
    int ch  = (e & 15) << 2;
    f32x4 cv = *(const f32x4*)&cb[row*BN + (ch ^ ((row & 3) << 4))];
    long gidx = (long)(mbase + row)*COUT + nt*BN + ch;
    if constexpr (KSPLIT) {
      ntstore4(pdst + gidx, cv);
    } else {
      f32x4 vv = {0.f,0.f,0.f,0.f}, ii = {0.f,0.f,0.f,0.f};
      if (t != 0) { vv = ntload4(vst + gidx); ii = ntload4(ist + gidx); }
      unsigned short zs[4];
#pragma unroll
      for (int s = 0; s < 4; s++) {
        float vdec = vv[s] + DTM*((0.0f - vv[s]) + ii[s]);
        bool z = (vdec - VTH) > 0.0f;
        vv[s] = z ? 0.0f : vdec;
        ii[s] = SYN*ii[s] + cv[s];
        zs[s] = z ? 0x3F80 : 0;
      }
      ntstore4(vst + gidx, vv);
      ntstore4(ist + gidx, ii);
      if constexpr (POOLZ)
        *(ushort4*)&zb[row*BN + ch] = make_ushort4(zs[0],zs[1],zs[2],zs[3]);
    }
  }

  if constexpr (POOLZ) {
    __syncthreads();
    constexpr int WP = WI/2, PR = ROWS/2, CH16 = BN/8;
    for (int c = tid; c < PR*WP*CH16; c += THREADS) {
      int ppx = c / CH16, ck = c % CH16;
      int py = ppx / WP, px = ppx % WP;
      int b0_ = ((2*py)*WI + 2*px)*BN + ck*8;
      u32x4 q0 = *(const u32x4*)(zb + b0_);
      u32x4 q1 = *(const u32x4*)(zb + b0_ + BN);
      u32x4 q2 = *(const u32x4*)(zb + b0_ + WI*BN);
      u32x4 q3 = *(const u32x4*)(zb + b0_ + WI*BN + BN);
      u32x4 vo = (q0|q1)|(q2|q3);
      long g = ((long)(b*(HIM/2) + (y0>>1) + py)*WP + px)*COUT + nt*BN + ck*8;
      *(u32x4*)(zpool + g) = vo;
    }
  }
}

// ---------------------------------------------------------------------------
// k5 body: sum conv4 half-K partials + LIF4 + 2x2 pool + FC(4096->10) + LI +
// noise + running max. 32 blocks x 256 thr.
// ---------------------------------------------------------------------------
DEV void k5_body(char* smem, int bid,
    const float* __restrict__ p0, const float* __restrict__ p1,
    float* __restrict__ v4, float* __restrict__ i4,
    const float* __restrict__ wfc, const float* __restrict__ noise,
    float* __restrict__ vl, float* __restrict__ il, float* __restrict__ dout, int t)
{
  unsigned long long* zbits = (unsigned long long*)smem;   // [64][4]
  unsigned long long* pb = zbits + 64*4;                   // [64]
  float* red = (float*)(pb + 64);                          // [4][10]
  int tid = threadIdx.x, b = bid;
  int px = tid >> 2, cq = tid & 3;
  long base = ((long)b*64 + px)*256 + cq*64;
  unsigned long long mask = 0ull;
#pragma unroll
  for (int q = 0; q < 16; q++) {
    f32x4 pa = ntload4(p0 + base + q*4);
    f32x4 pbv = ntload4(p1 + base + q*4);
    float vv[4] = {0.f,0.f,0.f,0.f}, ii[4] = {0.f,0.f,0.f,0.f};
    if (t != 0) {
      float4 v4v = *(const float4*)(v4 + base + q*4);
      float4 i4v = *(const float4*)(i4 + base + q*4);
      vv[0]=v4v.x; vv[1]=v4v.y; vv[2]=v4v.z; vv[3]=v4v.w;
      ii[0]=i4v.x; ii[1]=i4v.y; ii[2]=i4v.z; ii[3]=i4v.w;
    }
#pragma unroll
    for (int s = 0; s < 4; s++) {
      float cv = pa[s] + pbv[s];
      float vdec = vv[s] + DTM*((0.0f - vv[s]) + ii[s]);
      bool z = (vdec - VTH) > 0.0f;
      vv[s] = z ? 0.0f : vdec;
      ii[s] = SYN*ii[s] + cv;
      if (z) mask |= (1ull << (q*4 + s));
    }
    *(float4*)(v4 + base + q*4) = make_float4(vv[0],vv[1],vv[2],vv[3]);
    *(float4*)(i4 + base + q*4) = make_float4(ii[0],ii[1],ii[2],ii[3]);
  }
  zbits[px*4 + cq] = mask;
  __syncthreads();
  if (tid < 64) {
    int py = tid >> 4, rm = tid & 15, pxx = rm >> 2, c4 = rm & 3;
    int p00 = (2*py)*8 + 2*pxx;
    pb[tid] = zbits[p00*4+c4] | zbits[(p00+1)*4+c4] | zbits[(p00+8)*4+c4] | zbits[(p00+9)*4+c4];
  }
  __syncthreads();
  float sums[10];
#pragma unroll
  for (int j = 0; j < 10; j++) sums[j] = 0.f;
#pragma unroll
  for (int q = 0; q < 16; q++) {
    int k = q*256 + tid;
    int c = k >> 4, s = k & 15, yy = s >> 2, xx = s & 3;
    unsigned long long bits = pb[yy*16 + xx*4 + (c >> 6)];
    if ((bits >> (c & 63)) & 1ull) {
#pragma unroll
      for (int j = 0; j < 10; j++) sums[j] += wfc[j*4096 + k];
    }
  }
#pragma unroll
  for (int j = 0; j < 10; j++) {
    float v = sums[j];
    for (int off = 32; off; off >>= 1) v += __shfl_xor(v, off);
    if ((tid & 63) == 0) red[(tid >> 6)*10 + j] = v;
  }
  __syncthreads();
  if (tid < 10) {
    float o = red[tid] + red[10+tid] + red[20+tid] + red[30+tid];
    float vo = 0.f, io = 0.f;
    if (t != 0) { vo = vl[b*10 + tid]; io = il[b*10 + tid]; }
    float vn = vo + DTM*((0.0f - vo) + io);
    float inw = SYN*io + o;
    vl[b*10 + tid] = vn; il[b*10 + tid] = inw;
    float volt = vn + 0.001f*noise[((long)t*32 + b)*10 + tid];
    dout[b*10 + tid] = (t == 0) ? volt : fmaxf(dout[b*10 + tid], volt);
  }
}

// ---------------------------------------------------------------------------
// uber: one diagonal d of the time x layer wavefront. All 5 layer-segments in
// one launch are mutually independent (layer l works on t = d - l, consuming
// tensors produced in EARLIER launches; parity double-buffers prevent
// producer/consumer aliasing within a launch).
// Segments: [0,512) k1 | [512,1536) conv2 | [1536,2560) conv3 |
//           [2560,3072) conv4 | [3072,3104) k5.
// ---------------------------------------------------------------------------
__global__ __launch_bounds__(256, 4) void uber_kernel(
    const float* __restrict__ x, const float* __restrict__ noise,
    const float* __restrict__ w1, const float* __restrict__ wfc,
    float* v1, float* i1, float* v2, float* i2,
    float* v3, float* i3, float* v4, float* i4,
    unsigned short* z1a, unsigned short* z1b,
    unsigned short* z2pa, unsigned short* z2pb,
    unsigned short* z3pa, unsigned short* z3pb,
    float* p0a, float* p0b, float* p1a, float* p1b,
    const unsigned short* wb2h, const unsigned short* wb2m, const unsigned short* wb2l,
    const unsigned short* wb3h, const unsigned short* wb3m, const unsigned short* wb3l,
    const unsigned short* wb4h, const unsigned short* wb4m, const unsigned short* wb4l,
    float* vl, float* il, float* dout, int d)
{
  __shared__ __align__(16) char smem[24576];
  int bid = blockIdx.x;
  if (bid < 512) {
    int t = d;
    if (t <= 15)
      k1_body(smem, bid, x, w1, v1, i1, (t & 1) ? z1b : z1a, t);
    return;
  }
  bid -= 512;
  if (bid < 1024) {
    int t = d - 1;
    if (t >= 0 && t <= 15)
      conv_body<4, 64,32,32,128, 64,2,false,true>(smem, bid,
          (t & 1) ? z1b : z1a, wb2h, wb2m, wb2l, v2, i2,
          (t & 1) ? z2pb : z2pa, nullptr, nullptr, t);
    return;
  }
  bid -= 1024;
  if (bid < 1024) {
    int t = d - 2;
    if (t >= 0 && t <= 15)
      conv_body<2,128,16,16,256,128,4,false,true>(smem, bid,
          (t & 1) ? z2pb : z2pa, wb3h, wb3m, wb3l, v3, i3,
          (t & 1) ? z3pb : z3pa, nullptr, nullptr, t);
    return;
  }
  bid -= 1024;
  if (bid < 512) {
    int t = d - 3;
    if (t >= 0 && t <= 15)
      conv_body<2,128, 8, 8,256,256,4,true,false>(smem, bid,
          (t & 1) ? z3pb : z3pa, wb4h, wb4m, wb4l, nullptr, nullptr, nullptr,
          (t & 1) ? p0b : p0a, (t & 1) ? p1b : p1a, t);
    return;
  }
  bid -= 512;
  {
    int t = d - 4;
    if (t >= 0 && t <= 15)
      k5_body(smem, bid, (t & 1) ? p0b : p0a, (t & 1) ? p1b : p1a,
              v4, i4, wfc, noise, vl, il, dout, t);
  }
}

// ---------------------------------------------------------------------------
extern "C" void kernel_launch(void* const* d_in, const int* in_sizes, int n_in,
                              void* d_out, int out_size, void* d_ws, size_t ws_size,
                              hipStream_t stream)
{
  const float* x     = (const float*)d_in[0];
  const float* noise = (const float*)d_in[1];
  const float* w1    = (const float*)d_in[2];
  const float* w2    = (const float*)d_in[3];
  const float* w3    = (const float*)d_in[4];
  const float* w4    = (const float*)d_in[5];
  const float* wfc   = (const float*)d_in[6];
  float* dout = (float*)d_out;

  char* ws = (char*)d_ws;
  size_t off = 0;
  auto alloc = [&](size_t bytes) -> char* {
    char* p = ws + off;
    off = (off + bytes + 255) & ~(size_t)255;
    return p;
  };
  float* v1 = (float*)alloc(2097152u*4); float* i1 = (float*)alloc(2097152u*4);
  float* v2 = (float*)alloc(4194304u*4); float* i2 = (float*)alloc(4194304u*4);
  float* v3 = (float*)alloc(2097152u*4); float* i3 = (float*)alloc(2097152u*4);
  float* v4 = (float*)alloc(524288u*4);  float* i4 = (float*)alloc(524288u*4);
  unsigned short* z1a  = (unsigned short*)alloc(2097152u*2);
  unsigned short* z1b  = (unsigned short*)alloc(2097152u*2);
  unsigned short* z2pa = (unsigned short*)alloc(1048576u*2);
  unsigned short* z2pb = (unsigned short*)alloc(1048576u*2);
  unsigned short* z3pa = (unsigned short*)alloc(524288u*2);
  unsigned short* z3pb = (unsigned short*)alloc(524288u*2);
  float* p0a = (float*)alloc(524288u*4);
  float* p0b = (float*)alloc(524288u*4);
  float* p1a = (float*)alloc(524288u*4);
  float* p1b = (float*)alloc(524288u*4);
  float* vl = (float*)alloc(1280);
  float* il = (float*)alloc(1280);
  unsigned short* wb2h = (unsigned short*)alloc(73728u*2);
  unsigned short* wb2m = (unsigned short*)alloc(73728u*2);
  unsigned short* wb2l = (unsigned short*)alloc(73728u*2);
  unsigned short* wb3h = (unsigned short*)alloc(294912u*2);
  unsigned short* wb3m = (unsigned short*)alloc(294912u*2);
  unsigned short* wb3l = (unsigned short*)alloc(294912u*2);
  unsigned short* wb4h = (unsigned short*)alloc(589824u*2);
  unsigned short* wb4m = (unsigned short*)alloc(589824u*2);
  unsigned short* wb4l = (unsigned short*)alloc(589824u*2);

  prep_kernel<<<3744, 256, 0, stream>>>(w2, w3, w4,
      wb2h, wb2m, wb2l, wb3h, wb3m, wb3l, wb4h, wb4m, wb4l);

  for (int d = 0; d < 20; d++) {
    uber_kernel<<<3104, 256, 0, stream>>>(
        x, noise, w1, wfc,
        v1, i1, v2, i2, v3, i3, v4, i4,
        z1a, z1b, z2pa, z2pb, z3pa, z3pb,
        p0a, p0b, p1a, p1b,
        wb2h, wb2m, wb2l, wb3h, wb3m, wb3l, wb4h, wb4m, wb4l,
        vl, il, dout, d);
  }
}

// Round 14
// 983.247 us; speedup vs baseline: 2.7129x; 2.7129x over previous
//
#include <hip/hip_runtime.h>

typedef __attribute__((ext_vector_type(8))) short short8;
typedef __attribute__((ext_vector_type(4))) float f32x4;
typedef __attribute__((ext_vector_type(4))) unsigned int u32x4;

#define DEV static __device__ __forceinline__

DEV unsigned short f2bf(float f){
  unsigned int u = __float_as_uint(f);
  u += 0x7FFFu + ((u >> 16) & 1u);
  return (unsigned short)(u >> 16);
}
DEV float bf2f(unsigned short h){ return __uint_as_float(((unsigned int)h) << 16); }

#define DTM 0.1f   /* DT*TAU_MEM_INV */
#define SYN 0.8f   /* 1 - DT*TAU_SYN_INV */
#define VTH 0.2f

// ---------------------------------------------------------------------------
// prep: weights -> MFMA-fragment-major bf16 hi/mid/lo digit layout (as r12).
// ---------------------------------------------------------------------------
__global__ __launch_bounds__(256) void prep_kernel(
    const float* __restrict__ w2, const float* __restrict__ w3, const float* __restrict__ w4,
    unsigned short* __restrict__ wb2h, unsigned short* __restrict__ wb2m, unsigned short* __restrict__ wb2l,
    unsigned short* __restrict__ wb3h, unsigned short* __restrict__ wb3m, unsigned short* __restrict__ wb3l,
    unsigned short* __restrict__ wb4h, unsigned short* __restrict__ wb4m, unsigned short* __restrict__ wb4l)
{
  const int N2 = 9*128*64, N3 = 9*256*128, N4 = 9*256*256;
  int tid = blockIdx.x*256 + threadIdx.x;
  if (tid < N2) {
    int j = tid & 7, co = (tid >> 3) & 127, q = (tid >> 3) >> 7;
    int kg = q & 3, sg = q >> 2;
    int tap = sg >> 1, ks = sg & 1;
    int ci = ks*32 + kg*8 + j;
    float w = w2[(co*64 + ci)*9 + tap];
    unsigned short h = f2bf(w);   float r1 = w - bf2f(h);
    unsigned short m = f2bf(r1);  float r2 = r1 - bf2f(m);
    wb2h[tid] = h; wb2m[tid] = m; wb2l[tid] = f2bf(r2);
    return;
  }
  tid -= N2;
  if (tid < N3) {
    int j = tid & 7, co = (tid >> 3) & 255, q = (tid >> 3) >> 8;
    int kg = q & 3, sg = q >> 2;
    int p = sg >> 1, ks = sg & 1, tap = p >> 1, cs = p & 1;
    int ci = cs*64 + ks*32 + kg*8 + j;
    float w = w3[(co*128 + ci)*9 + tap];
    unsigned short h = f2bf(w);   float r1 = w - bf2f(h);
    unsigned short m = f2bf(r1);  float r2 = r1 - bf2f(m);
    wb3h[tid] = h; wb3m[tid] = m; wb3l[tid] = f2bf(r2);
    return;
  }
  tid -= N3;
  if (tid < N4) {
    int j = tid & 7, co = (tid >> 3) & 255, q = (tid >> 3) >> 8;
    int kg = q & 3, sg = q >> 2;
    int hh = sg / 36, sl = sg % 36;
    int p = sl >> 1, ks = sl & 1, tap = p >> 1, cs = p & 1;
    int ci = hh*128 + cs*64 + ks*32 + kg*8 + j;
    float w = w4[(co*256 + ci)*9 + tap];
    unsigned short h = f2bf(w);   float r1 = w - bf2f(h);
    unsigned short m = f2bf(r1);  float r2 = r1 - bf2f(m);
    wb4h[tid] = h; wb4m[tid] = m; wb4l[tid] = f2bf(r2);
  }
}

// ---------------------------------------------------------------------------
// K1: conv1 (fp32 direct, 3->64) + LIF1, ALL 16 timesteps in-kernel, state in
// registers. grid 512 = 32 imgs x 16 row-pairs; z1_all[t] written per step.
// ---------------------------------------------------------------------------
__global__ __launch_bounds__(256, 4) void k1_time(
    const float* __restrict__ x, const float* __restrict__ w1,
    unsigned short* __restrict__ z1_all)
{
  __shared__ float xs[3][4][34];
  __shared__ float wl[27][64];
  int tid = threadIdx.x;
  int b = blockIdx.x >> 4, y0 = (blockIdx.x & 15) * 2;
  for (int e = tid; e < 27*64; e += 256) {
    int row = e >> 6, co = e & 63;
    int ci = row % 3, tap = row / 3, ky = tap/3, kx = tap%3;
    wl[row][co] = w1[((co*3+ci)*3+ky)*3+kx];
  }
  int px = tid >> 2, cg = tid & 3;
  int ly = px >> 5, lx = px & 31;
  int m_g = b*1024 + (y0+ly)*32 + lx;

  float vv[16], ii[16];
#pragma unroll
  for (int q = 0; q < 16; q++) { vv[q] = 0.f; ii[q] = 0.f; }

  for (int t = 0; t < 16; t++) {
    __syncthreads();   // protect xs reuse
    for (int e = tid; e < 3*4*34; e += 256) {
      int ci = e/136, r2 = e%136, r = r2/34, xi = r2%34;
      int y = y0 - 1 + r, xg = xi - 1;
      float v = 0.f;
      if (y >= 0 && y < 32 && xg >= 0 && xg < 32)
        v = x[((t*32 + b)*3 + ci)*1024 + y*32 + xg];
      xs[ci][r][xi] = v;
    }
    __syncthreads();
    float acc[16];
#pragma unroll
    for (int q = 0; q < 16; q++) acc[q] = 0.f;
#pragma unroll
    for (int ky = 0; ky < 3; ky++)
#pragma unroll
      for (int kx = 0; kx < 3; kx++)
#pragma unroll
        for (int ci = 0; ci < 3; ci++) {
          float xv = xs[ci][ly+ky][lx+kx];
          const float4* wr = (const float4*)&wl[(ky*3+kx)*3+ci][cg*16];
#pragma unroll
          for (int q = 0; q < 4; q++) {
            float4 w4 = wr[q];
            acc[q*4+0] = fmaf(xv, w4.x, acc[q*4+0]);
            acc[q*4+1] = fmaf(xv, w4.y, acc[q*4+1]);
            acc[q*4+2] = fmaf(xv, w4.z, acc[q*4+2]);
            acc[q*4+3] = fmaf(xv, w4.w, acc[q*4+3]);
          }
        }
    unsigned short zb[16];
#pragma unroll
    for (int q = 0; q < 16; q++) {
      float vdec = vv[q] + DTM*((0.0f - vv[q]) + ii[q]);
      bool z = (vdec - VTH) > 0.0f;
      vv[q] = z ? 0.0f : vdec;
      ii[q] = SYN*ii[q] + acc[q];
      zb[q] = z ? 0x3F80 : 0;
    }
    unsigned short* z1 = z1_all + (long)t*2097152;
    u32x4 za, zc;
    za[0]=zb[0]|((unsigned)zb[1]<<16); za[1]=zb[2]|((unsigned)zb[3]<<16);
    za[2]=zb[4]|((unsigned)zb[5]<<16); za[3]=zb[6]|((unsigned)zb[7]<<16);
    zc[0]=zb[8]|((unsigned)zb[9]<<16); zc[1]=zb[10]|((unsigned)zb[11]<<16);
    zc[2]=zb[12]|((unsigned)zb[13]<<16); zc[3]=zb[14]|((unsigned)zb[15]<<16);
    *(u32x4*)(z1 + m_g*64 + cg*16) = za;
    *(u32x4*)(z1 + m_g*64 + cg*16 + 8) = zc;
  }
}

// ---------------------------------------------------------------------------
// Time-looped implicit-GEMM conv (3x3 SAME) over binary spikes, bf16
// hi/mid/lo 3-digit MFMA. ALL 16 timesteps in one kernel; LIF state (v,i)
// lives in REGISTERS -- zero state HBM traffic. A staged per-t in LDS
// ([ch-group][slot]); B per-lane from fragment-major global (L2-resident,
// this kernel's weights alone in L2), cur/next register double buffer,
// rolled K-loop. HALVES=2: full K as two sequential half-K accumulators
// summed at the end (bit-identical to r11's passing conv4). Epilogue: LDS C
// re-tile -> per-thread LIF on reg state -> fused 2x2 spike max-pool (OR).
// ---------------------------------------------------------------------------
template<int MF, int CIN_A, int HALVES, int WI, int HIM, int COUT, int CIN_SRC,
         int NT, int ZSRC_STEP, int ZDST_STEP>
__global__ __launch_bounds__(256, 3) void conv_time(
    const unsigned short* __restrict__ zsrc_all,
    const unsigned short* __restrict__ wbh, const unsigned short* __restrict__ wbm,
    const unsigned short* __restrict__ wbl,
    unsigned short* __restrict__ zpool_all)
{
  constexpr int THREADS = 256;
  constexpr int BM = MF*16;
  constexpr int BN = 64;
  constexpr int ROWS = BM/WI;
  constexpr int SLOTW = WI+2;
  constexpr int SLOTS = (ROWS+2)*SLOTW;
  constexpr int KHALF = CIN_A/HALVES;
  constexpr int CPH = KHALF/64;
  constexpr int NSC = 9*CPH;
  constexpr int MT_PER_B = (HIM*WI)/BM;
  constexpr int ACH = CIN_A/8;
  constexpr int ACHUNKS = SLOTS*ACH;
  constexpr int GSTRIDE = (SLOTS+1)*16;
  constexpr int ABYTES = ACH*GSTRIDE;
  constexpr int CBYTES = BM*BN*4;
  constexpr int EBYTES = CBYTES + BM*BN*2;
  constexpr int LDSB = ABYTES > EBYTES ? ABYTES : EBYTES;
  constexpr int ITER = (BM*BN/4)/THREADS;
  static_assert(LDSB <= 32*1024, "LDS");

  __shared__ __align__(16) char smem[LDSB];

  int tid = threadIdx.x;
  int rem = blockIdx.x;
  int nt = 0;
  if constexpr (NT > 1) { nt = rem % NT; rem /= NT; }
  int b = rem / MT_PER_B;
  int y0 = (rem % MT_PER_B) * ROWS;
  int lane = tid & 63, wn = tid >> 6;
  int kg = lane >> 4;

  int abase[MF];
#pragma unroll
  for (int mf = 0; mf < MF; mf++) {
    int pl = mf*16 + (lane & 15);
    int yl = pl / WI, xl = pl % WI;
    abase[mf] = kg*GSTRIDE + (yl*SLOTW + xl)*16;
  }

  int co_g = nt*BN + wn*16 + (lane & 15);
  const long bstep = (long)4*COUT*8;
  const long blane = ((long)kg*COUT + co_g)*8;

  // LIF state in registers (statically indexed)
  f32x4 vreg[ITER], ireg[ITER];
#pragma unroll
  for (int k = 0; k < ITER; k++) {
    vreg[k][0]=0.f; vreg[k][1]=0.f; vreg[k][2]=0.f; vreg[k][3]=0.f;
    ireg[k][0]=0.f; ireg[k][1]=0.f; ireg[k][2]=0.f; ireg[k][3]=0.f;
  }

  for (int t = 0; t < 16; t++) {
    const unsigned short* zsrc = zsrc_all + (long)t*ZSRC_STEP;
    __syncthreads();                     // smem free of previous epilogue
    for (int ch = tid; ch < ACHUNKS; ch += THREADS) {
      int slot = ch / ACH, g = ch % ACH;
      int yr = slot / SLOTW, xr = slot % SLOTW;
      int y = y0 + yr - 1, xg = xr - 1;
      u32x4 val; val[0]=0; val[1]=0; val[2]=0; val[3]=0;
      if (y >= 0 && y < HIM && xg >= 0 && xg < WI)
        val = *(const u32x4*)(zsrc + ((long)(b*HIM + y)*WI + xg)*CIN_SRC + g*8);
      *(u32x4*)(smem + g*GSTRIDE + slot*16) = val;
    }
    __syncthreads();

    f32x4 accsum[MF];
#pragma unroll
    for (int mf = 0; mf < MF; mf++) {
      accsum[mf][0]=0.f; accsum[mf][1]=0.f; accsum[mf][2]=0.f; accsum[mf][3]=0.f;
    }

#pragma unroll
    for (int hh = 0; hh < HALVES; hh++) {
      f32x4 acc[MF];
#pragma unroll
      for (int mf = 0; mf < MF; mf++) {
        acc[mf][0]=0.f; acc[mf][1]=0.f; acc[mf][2]=0.f; acc[mf][3]=0.f;
      }
      long bo = blane + (long)(hh*NSC*2)*bstep;
      short8 ch0 = *(const short8*)(wbh + bo);
      short8 cm0 = *(const short8*)(wbm + bo);
      short8 cl0 = *(const short8*)(wbl + bo);
      short8 ch1 = *(const short8*)(wbh + bo + bstep);
      short8 cm1 = *(const short8*)(wbm + bo + bstep);
      short8 cl1 = *(const short8*)(wbl + bo + bstep);

#pragma unroll 1
      for (int sc = 0; sc < NSC; sc++) {
        long bon = bo + ((sc + 1 < NSC) ? 2*bstep : 0);
        short8 nh0 = *(const short8*)(wbh + bon);
        short8 nm0 = *(const short8*)(wbm + bon);
        short8 nl0 = *(const short8*)(wbl + bon);
        short8 nh1 = *(const short8*)(wbh + bon + bstep);
        short8 nm1 = *(const short8*)(wbm + bon + bstep);
        short8 nl1 = *(const short8*)(wbl + bon + bstep);

        int tap, cs;
        if constexpr (CPH == 1) { tap = sc; cs = 0; }
        else { tap = sc >> 1; cs = sc & 1; }
        int ty = (tap*171) >> 9;
        int tx = tap - ty*3;
        int base0 = (hh*(KHALF/8) + cs*8)*GSTRIDE + (ty*SLOTW + tx)*16;

        short8 a0[MF], a1[MF];
#pragma unroll
        for (int mf = 0; mf < MF; mf++)
          a0[mf] = *(const short8*)(smem + abase[mf] + base0);
#pragma unroll
        for (int mf = 0; mf < MF; mf++)
          a1[mf] = *(const short8*)(smem + abase[mf] + base0 + 4*GSTRIDE);

#pragma unroll
        for (int mf = 0; mf < MF; mf++)
          acc[mf] = __builtin_amdgcn_mfma_f32_16x16x32_bf16(a0[mf], ch0, acc[mf], 0, 0, 0);
#pragma unroll
        for (int mf = 0; mf < MF; mf++)
          acc[mf] = __builtin_amdgcn_mfma_f32_16x16x32_bf16(a0[mf], cm0, acc[mf], 0, 0, 0);
#pragma unroll
        for (int mf = 0; mf < MF; mf++)
          acc[mf] = __builtin_amdgcn_mfma_f32_16x16x32_bf16(a0[mf], cl0, acc[mf], 0, 0, 0);
#pragma unroll
        for (int mf = 0; mf < MF; mf++)
          acc[mf] = __builtin_amdgcn_mfma_f32_16x16x32_bf16(a1[mf], ch1, acc[mf], 0, 0, 0);
#pragma unroll
        for (int mf = 0; mf < MF; mf++)
          acc[mf] = __builtin_amdgcn_mfma_f32_16x16x32_bf16(a1[mf], cm1, acc[mf], 0, 0, 0);
#pragma unroll
        for (int mf = 0; mf < MF; mf++)
          acc[mf] = __builtin_amdgcn_mfma_f32_16x16x32_bf16(a1[mf], cl1, acc[mf], 0, 0, 0);

        ch0 = nh0; cm0 = nm0; cl0 = nl0;
        ch1 = nh1; cm1 = nm1; cl1 = nl1;
        bo = bon;
      }

      if constexpr (HALVES == 1) {
#pragma unroll
        for (int mf = 0; mf < MF; mf++) accsum[mf] = acc[mf];
      } else {
#pragma unroll
        for (int mf = 0; mf < MF; mf++)
#pragma unroll
          for (int r = 0; r < 4; r++) accsum[mf][r] += acc[mf][r];
      }
    }

    // ---- epilogue: C re-tile via LDS -> per-thread LIF on register state ----
    __syncthreads();                     // A-LDS dead; reuse
    float* cb = (float*)smem;
    unsigned short* zb = (unsigned short*)(smem + CBYTES);
    {
      int chn = wn*16 + (lane & 15);
#pragma unroll
      for (int mf = 0; mf < MF; mf++)
#pragma unroll
        for (int r = 0; r < 4; r++) {
          int pix = mf*16 + (lane >> 4)*4 + r;
          cb[pix*BN + (chn ^ ((pix & 3) << 4))] = accsum[mf][r];
        }
    }
    __syncthreads();
#pragma unroll
    for (int k = 0; k < ITER; k++) {
      int e = k*THREADS + tid;
      int row = e >> 4;
      int ch  = (e & 15) << 2;
      f32x4 cv = *(const f32x4*)&cb[row*BN + (ch ^ ((row & 3) << 4))];
      unsigned short zs[4];
#pragma unroll
      for (int s = 0; s < 4; s++) {
        float vdec = vreg[k][s] + DTM*((0.0f - vreg[k][s]) + ireg[k][s]);
        bool z = (vdec - VTH) > 0.0f;
        vreg[k][s] = z ? 0.0f : vdec;
        ireg[k][s] = SYN*ireg[k][s] + cv[s];
        zs[s] = z ? 0x3F80 : 0;
      }
      *(ushort4*)&zb[row*BN + ch] = make_ushort4(zs[0],zs[1],zs[2],zs[3]);
    }

    __syncthreads();
    unsigned short* zpool = zpool_all + (long)t*ZDST_STEP;
    constexpr int WP = WI/2, PR = ROWS/2, CH16 = BN/8;
    for (int c = tid; c < PR*WP*CH16; c += THREADS) {
      int ppx = c / CH16, ck = c % CH16;
      int py = ppx / WP, px = ppx % WP;
      int b0_ = ((2*py)*WI + 2*px)*BN + ck*8;
      u32x4 q0 = *(const u32x4*)(zb + b0_);
      u32x4 q1 = *(const u32x4*)(zb + b0_ + BN);
      u32x4 q2 = *(const u32x4*)(zb + b0_ + WI*BN);
      u32x4 q3 = *(const u32x4*)(zb + b0_ + WI*BN + BN);
      u32x4 vo = (q0|q1)|(q2|q3);
      long g = ((long)(b*(HIM/2) + (y0>>1) + py)*WP + px)*COUT + nt*BN + ck*8;
      *(u32x4*)(zpool + g) = vo;
    }
  }
}

// ---------------------------------------------------------------------------
// K5: FC(4096->10) over pooled L4 spikes + LI + noise + running max, all 16
// timesteps in-kernel, LI state in registers. 32 blocks x 512 threads.
// ---------------------------------------------------------------------------
__global__ __launch_bounds__(512) void k5_time(
    const unsigned short* __restrict__ z4p_all, const float* __restrict__ wfc,
    const float* __restrict__ noise, float* __restrict__ dout)
{
  __shared__ float red[8][10];
  int tid = threadIdx.x, b = blockIdx.x;
  float vo = 0.f, io = 0.f, mx = 0.f;

  for (int t = 0; t < 16; t++) {
    __syncthreads();                     // red free of previous step
    const unsigned short* z4p = z4p_all + (long)t*131072;
    float sums[10];
#pragma unroll
    for (int j = 0; j < 10; j++) sums[j] = 0.f;
#pragma unroll
    for (int q = 0; q < 8; q++) {
      int k = q*512 + tid;
      int c = k >> 4, s = k & 15, py = s >> 2, px = s & 3;
      float zf = bf2f(z4p[((b*4 + py)*4 + px)*256 + c]);
#pragma unroll
      for (int j = 0; j < 10; j++)
        sums[j] = fmaf(zf, wfc[j*4096 + k], sums[j]);
    }
#pragma unroll
    for (int j = 0; j < 10; j++) {
      float v = sums[j];
      for (int off = 32; off; off >>= 1) v += __shfl_xor(v, off);
      if ((tid & 63) == 0) red[tid >> 6][j] = v;
    }
    __syncthreads();
    if (tid < 10) {
      float o = 0.f;
#pragma unroll
      for (int w = 0; w < 8; w++) o += red[w][tid];
      float vn = vo + DTM*((0.0f - vo) + io);
      float inw = SYN*io + o;
      vo = vn; io = inw;
      float volt = vn + 0.001f*noise[((long)t*32 + b)*10 + tid];
      mx = (t == 0) ? volt : fmaxf(mx, volt);
    }
  }
  if (tid < 10) dout[b*10 + tid] = mx;
}

// ---------------------------------------------------------------------------
extern "C" void kernel_launch(void* const* d_in, const int* in_sizes, int n_in,
                              void* d_out, int out_size, void* d_ws, size_t ws_size,
                              hipStream_t stream)
{
  const float* x     = (const float*)d_in[0];
  const float* noise = (const float*)d_in[1];
  const float* w1    = (const float*)d_in[2];
  const float* w2    = (const float*)d_in[3];
  const float* w3    = (const float*)d_in[4];
  const float* w4    = (const float*)d_in[5];
  const float* wfc   = (const float*)d_in[6];
  float* dout = (float*)d_out;

  char* ws = (char*)d_ws;
  size_t off = 0;
  auto alloc = [&](size_t bytes) -> char* {
    char* p = ws + off;
    off = (off + bytes + 255) & ~(size_t)255;
    return p;
  };
  unsigned short* z1  = (unsigned short*)alloc(16u*2097152u*2);  // [16][32][32][32][64]
  unsigned short* z2p = (unsigned short*)alloc(16u*1048576u*2);  // [16][32][16][16][128]
  unsigned short* z3p = (unsigned short*)alloc(16u*524288u*2);   // [16][32][8][8][256]
  unsigned short* z4p = (unsigned short*)alloc(16u*131072u*2);   // [16][32][4][4][256]
  unsigned short* wb2h = (unsigned short*)alloc(73728u*2);
  unsigned short* wb2m = (unsigned short*)alloc(73728u*2);
  unsigned short* wb2l = (unsigned short*)alloc(73728u*2);
  unsigned short* wb3h = (unsigned short*)alloc(294912u*2);
  unsigned short* wb3m = (unsigned short*)alloc(294912u*2);
  unsigned short* wb3l = (unsigned short*)alloc(294912u*2);
  unsigned short* wb4h = (unsigned short*)alloc(589824u*2);
  unsigned short* wb4m = (unsigned short*)alloc(589824u*2);
  unsigned short* wb4l = (unsigned short*)alloc(589824u*2);

  prep_kernel<<<3744, 256, 0, stream>>>(w2, w3, w4,
      wb2h, wb2m, wb2l, wb3h, wb3m, wb3l, wb4h, wb4m, wb4l);

  // L1: conv1+LIF1, all t (state in regs), grid 512
  k1_time<<<512, 256, 0, stream>>>(x, w1, z1);
  // L2: 64->128 @32x32, BM=64 BN=64 NT=2, all t, grid 1024
  conv_time<4, 64,1,32,32,128, 64,2,2097152,1048576><<<1024, 256, 0, stream>>>(
      z1, wb2h, wb2m, wb2l, z2p);
  // L3: 128->256 @16x16 pooled-in, BM=32 BN=64 NT=4, all t, grid 1024
  conv_time<2,128,1,16,16,256,128,4,1048576,524288><<<1024, 256, 0, stream>>>(
      z2p, wb3h, wb3m, wb3l, z3p);
  // L4: 256->256 @8x8 pooled-in, FULL K (2 halves), BM=16 NT=4, all t, grid 512
  conv_time<1,256,2, 8, 8,256,256,4,524288,131072><<<512, 256, 0, stream>>>(
      z3p, wb4h, wb4m, wb4l, z4p);
  // FC + LI + max, all t, grid 32
  k5_time<<<32, 512, 0, stream>>>(z4p, wfc, noise, dout);
}

// Round 15
// 982.661 us; speedup vs baseline: 2.7145x; 1.0006x over previous
//
#include <hip/hip_runtime.h>

typedef __attribute__((ext_vector_type(8))) short short8;
typedef __attribute__((ext_vector_type(4))) float f32x4;
typedef __attribute__((ext_vector_type(4))) unsigned int u32x4;

#define DEV static __device__ __forceinline__

DEV unsigned short f2bf(float f){
  unsigned int u = __float_as_uint(f);
  u += 0x7FFFu + ((u >> 16) & 1u);
  return (unsigned short)(u >> 16);
}
DEV float bf2f(unsigned short h){ return __uint_as_float(((unsigned int)h) << 16); }

#define DTM 0.1f   /* DT*TAU_MEM_INV */
#define SYN 0.8f   /* 1 - DT*TAU_SYN_INV */
#define VTH 0.2f

// ---------------------------------------------------------------------------
// prep: weights -> MFMA-fragment-major bf16 hi/mid/lo digit layout (as r12).
// ---------------------------------------------------------------------------
__global__ __launch_bounds__(256) void prep_kernel(
    const float* __restrict__ w2, const float* __restrict__ w3, const float* __restrict__ w4,
    unsigned short* __restrict__ wb2h, unsigned short* __restrict__ wb2m, unsigned short* __restrict__ wb2l,
    unsigned short* __restrict__ wb3h, unsigned short* __restrict__ wb3m, unsigned short* __restrict__ wb3l,
    unsigned short* __restrict__ wb4h, unsigned short* __restrict__ wb4m, unsigned short* __restrict__ wb4l)
{
  const int N2 = 9*128*64, N3 = 9*256*128, N4 = 9*256*256;
  int tid = blockIdx.x*256 + threadIdx.x;
  if (tid < N2) {
    int j = tid & 7, co = (tid >> 3) & 127, q = (tid >> 3) >> 7;
    int kg = q & 3, sg = q >> 2;
    int tap = sg >> 1, ks = sg & 1;
    int ci = ks*32 + kg*8 + j;
    float w = w2[(co*64 + ci)*9 + tap];
    unsigned short h = f2bf(w);   float r1 = w - bf2f(h);
    unsigned short m = f2bf(r1);  float r2 = r1 - bf2f(m);
    wb2h[tid] = h; wb2m[tid] = m; wb2l[tid] = f2bf(r2);
    return;
  }
  tid -= N2;
  if (tid < N3) {
    int j = tid & 7, co = (tid >> 3) & 255, q = (tid >> 3) >> 8;
    int kg = q & 3, sg = q >> 2;
    int p = sg >> 1, ks = sg & 1, tap = p >> 1, cs = p & 1;
    int ci = cs*64 + ks*32 + kg*8 + j;
    float w = w3[(co*128 + ci)*9 + tap];
    unsigned short h = f2bf(w);   float r1 = w - bf2f(h);
    unsigned short m = f2bf(r1);  float r2 = r1 - bf2f(m);
    wb3h[tid] = h; wb3m[tid] = m; wb3l[tid] = f2bf(r2);
    return;
  }
  tid -= N3;
  if (tid < N4) {
    int j = tid & 7, co = (tid >> 3) & 255, q = (tid >> 3) >> 8;
    int kg = q & 3, sg = q >> 2;
    int hh = sg / 36, sl = sg % 36;
    int p = sl >> 1, ks = sl & 1, tap = p >> 1, cs = p & 1;
    int ci = hh*128 + cs*64 + ks*32 + kg*8 + j;
    float w = w4[(co*256 + ci)*9 + tap];
    unsigned short h = f2bf(w);   float r1 = w - bf2f(h);
    unsigned short m = f2bf(r1);  float r2 = r1 - bf2f(m);
    wb4h[tid] = h; wb4m[tid] = m; wb4l[tid] = f2bf(r2);
  }
}

// ---------------------------------------------------------------------------
// K1: conv1 (fp32 direct, 3->64) + LIF1, ALL 16 timesteps in-kernel, state in
// registers. grid 512 = 32 imgs x 16 row-pairs; z1_all[t] written per step.
// ---------------------------------------------------------------------------
__global__ __launch_bounds__(256, 4) void k1_time(
    const float* __restrict__ x, const float* __restrict__ w1,
    unsigned short* __restrict__ z1_all)
{
  __shared__ float xs[3][4][34];
  __shared__ float wl[27][64];
  int tid = threadIdx.x;
  int b = blockIdx.x >> 4, y0 = (blockIdx.x & 15) * 2;
  for (int e = tid; e < 27*64; e += 256) {
    int row = e >> 6, co = e & 63;
    int ci = row % 3, tap = row / 3, ky = tap/3, kx = tap%3;
    wl[row][co] = w1[((co*3+ci)*3+ky)*3+kx];
  }
  int px = tid >> 2, cg = tid & 3;
  int ly = px >> 5, lx = px & 31;
  int m_g = b*1024 + (y0+ly)*32 + lx;

  float vv[16], ii[16];
#pragma unroll
  for (int q = 0; q < 16; q++) { vv[q] = 0.f; ii[q] = 0.f; }

  for (int t = 0; t < 16; t++) {
    __syncthreads();   // protect xs reuse
    for (int e = tid; e < 3*4*34; e += 256) {
      int ci = e/136, r2 = e%136, r = r2/34, xi = r2%34;
      int y = y0 - 1 + r, xg = xi - 1;
      float v = 0.f;
      if (y >= 0 && y < 32 && xg >= 0 && xg < 32)
        v = x[((t*32 + b)*3 + ci)*1024 + y*32 + xg];
      xs[ci][r][xi] = v;
    }
    __syncthreads();
    float acc[16];
#pragma unroll
    for (int q = 0; q < 16; q++) acc[q] = 0.f;
#pragma unroll
    for (int ky = 0; ky < 3; ky++)
#pragma unroll
      for (int kx = 0; kx < 3; kx++)
#pragma unroll
        for (int ci = 0; ci < 3; ci++) {
          float xv = xs[ci][ly+ky][lx+kx];
          const float4* wr = (const float4*)&wl[(ky*3+kx)*3+ci][cg*16];
#pragma unroll
          for (int q = 0; q < 4; q++) {
            float4 w4 = wr[q];
            acc[q*4+0] = fmaf(xv, w4.x, acc[q*4+0]);
            acc[q*4+1] = fmaf(xv, w4.y, acc[q*4+1]);
            acc[q*4+2] = fmaf(xv, w4.z, acc[q*4+2]);
            acc[q*4+3] = fmaf(xv, w4.w, acc[q*4+3]);
          }
        }
    unsigned short zb[16];
#pragma unroll
    for (int q = 0; q < 16; q++) {
      float vdec = vv[q] + DTM*((0.0f - vv[q]) + ii[q]);
      bool z = (vdec - VTH) > 0.0f;
      vv[q] = z ? 0.0f : vdec;
      ii[q] = SYN*ii[q] + acc[q];
      zb[q] = z ? 0x3F80 : 0;
    }
    unsigned short* z1 = z1_all + (long)t*2097152;
    u32x4 za, zc;
    za[0]=zb[0]|((unsigned)zb[1]<<16); za[1]=zb[2]|((unsigned)zb[3]<<16);
    za[2]=zb[4]|((unsigned)zb[5]<<16); za[3]=zb[6]|((unsigned)zb[7]<<16);
    zc[0]=zb[8]|((unsigned)zb[9]<<16); zc[1]=zb[10]|((unsigned)zb[11]<<16);
    zc[2]=zb[12]|((unsigned)zb[13]<<16); zc[3]=zb[14]|((unsigned)zb[15]<<16);
    *(u32x4*)(z1 + m_g*64 + cg*16) = za;
    *(u32x4*)(z1 + m_g*64 + cg*16 + 8) = zc;
  }
}

// ---------------------------------------------------------------------------
// Time-looped implicit-GEMM conv (3x3 SAME) over binary spikes, bf16
// hi/mid/lo 3-digit MFMA. ALL 16 timesteps in one kernel; LIF state (v,i)
// lives in REGISTERS -- zero state HBM traffic. A staged per-t in LDS
// ([ch-group][slot]); B per-lane from fragment-major global (L2-resident,
// this kernel's weights alone in L2), cur/next register double buffer,
// rolled K-loop. HALVES=2: full K as two sequential half-K accumulators
// summed at the end (bit-identical to r11's passing conv4). Epilogue: LDS C
// re-tile -> per-thread LIF on reg state -> fused 2x2 spike max-pool (OR).
// ---------------------------------------------------------------------------
template<int MF, int CIN_A, int HALVES, int WI, int HIM, int COUT, int CIN_SRC,
         int NT, int ZSRC_STEP, int ZDST_STEP>
__global__ __launch_bounds__(256, 3) void conv_time(
    const unsigned short* __restrict__ zsrc_all,
    const unsigned short* __restrict__ wbh, const unsigned short* __restrict__ wbm,
    const unsigned short* __restrict__ wbl,
    unsigned short* __restrict__ zpool_all)
{
  constexpr int THREADS = 256;
  constexpr int BM = MF*16;
  constexpr int BN = 64;
  constexpr int ROWS = BM/WI;
  constexpr int SLOTW = WI+2;
  constexpr int SLOTS = (ROWS+2)*SLOTW;
  constexpr int KHALF = CIN_A/HALVES;
  constexpr int CPH = KHALF/64;
  constexpr int NSC = 9*CPH;
  constexpr int MT_PER_B = (HIM*WI)/BM;
  constexpr int ACH = CIN_A/8;
  constexpr int ACHUNKS = SLOTS*ACH;
  constexpr int GSTRIDE = (SLOTS+1)*16;
  constexpr int ABYTES = ACH*GSTRIDE;
  constexpr int CBYTES = BM*BN*4;
  constexpr int EBYTES = CBYTES + BM*BN*2;
  constexpr int LDSB = ABYTES > EBYTES ? ABYTES : EBYTES;
  constexpr int ITER = (BM*BN/4)/THREADS;
  static_assert(LDSB <= 32*1024, "LDS");

  __shared__ __align__(16) char smem[LDSB];

  int tid = threadIdx.x;
  int rem = blockIdx.x;
  int nt = 0;
  if constexpr (NT > 1) { nt = rem % NT; rem /= NT; }
  int b = rem / MT_PER_B;
  int y0 = (rem % MT_PER_B) * ROWS;
  int lane = tid & 63, wn = tid >> 6;
  int kg = lane >> 4;

  int abase[MF];
#pragma unroll
  for (int mf = 0; mf < MF; mf++) {
    int pl = mf*16 + (lane & 15);
    int yl = pl / WI, xl = pl % WI;
    abase[mf] = kg*GSTRIDE + (yl*SLOTW + xl)*16;
  }

  int co_g = nt*BN + wn*16 + (lane & 15);
  const long bstep = (long)4*COUT*8;
  const long blane = ((long)kg*COUT + co_g)*8;

  // LIF state in registers (statically indexed)
  f32x4 vreg[ITER], ireg[ITER];
#pragma unroll
  for (int k = 0; k < ITER; k++) {
    vreg[k][0]=0.f; vreg[k][1]=0.f; vreg[k][2]=0.f; vreg[k][3]=0.f;
    ireg[k][0]=0.f; ireg[k][1]=0.f; ireg[k][2]=0.f; ireg[k][3]=0.f;
  }

  for (int t = 0; t < 16; t++) {
    const unsigned short* zsrc = zsrc_all + (long)t*ZSRC_STEP;
    __syncthreads();                     // smem free of previous epilogue
    for (int ch = tid; ch < ACHUNKS; ch += THREADS) {
      int slot = ch / ACH, g = ch % ACH;
      int yr = slot / SLOTW, xr = slot % SLOTW;
      int y = y0 + yr - 1, xg = xr - 1;
      u32x4 val; val[0]=0; val[1]=0; val[2]=0; val[3]=0;
      if (y >= 0 && y < HIM && xg >= 0 && xg < WI)
        val = *(const u32x4*)(zsrc + ((long)(b*HIM + y)*WI + xg)*CIN_SRC + g*8);
      *(u32x4*)(smem + g*GSTRIDE + slot*16) = val;
    }
    __syncthreads();

    f32x4 accsum[MF];
#pragma unroll
    for (int mf = 0; mf < MF; mf++) {
      accsum[mf][0]=0.f; accsum[mf][1]=0.f; accsum[mf][2]=0.f; accsum[mf][3]=0.f;
    }

#pragma unroll
    for (int hh = 0; hh < HALVES; hh++) {
      f32x4 acc[MF];
#pragma unroll
      for (int mf = 0; mf < MF; mf++) {
        acc[mf][0]=0.f; acc[mf][1]=0.f; acc[mf][2]=0.f; acc[mf][3]=0.f;
      }
      long bo = blane + (long)(hh*NSC*2)*bstep;
      short8 ch0 = *(const short8*)(wbh + bo);
      short8 cm0 = *(const short8*)(wbm + bo);
      short8 cl0 = *(const short8*)(wbl + bo);
      short8 ch1 = *(const short8*)(wbh + bo + bstep);
      short8 cm1 = *(const short8*)(wbm + bo + bstep);
      short8 cl1 = *(const short8*)(wbl + bo + bstep);

#pragma unroll 1
      for (int sc = 0; sc < NSC; sc++) {
        long bon = bo + ((sc + 1 < NSC) ? 2*bstep : 0);
        short8 nh0 = *(const short8*)(wbh + bon);
        short8 nm0 = *(const short8*)(wbm + bon);
        short8 nl0 = *(const short8*)(wbl + bon);
        short8 nh1 = *(const short8*)(wbh + bon + bstep);
        short8 nm1 = *(const short8*)(wbm + bon + bstep);
        short8 nl1 = *(const short8*)(wbl + bon + bstep);

        int tap, cs;
        if constexpr (CPH == 1) { tap = sc; cs = 0; }
        else { tap = sc >> 1; cs = sc & 1; }
        int ty = (tap*171) >> 9;
        int tx = tap - ty*3;
        int base0 = (hh*(KHALF/8) + cs*8)*GSTRIDE + (ty*SLOTW + tx)*16;

        short8 a0[MF], a1[MF];
#pragma unroll
        for (int mf = 0; mf < MF; mf++)
          a0[mf] = *(const short8*)(smem + abase[mf] + base0);
#pragma unroll
        for (int mf = 0; mf < MF; mf++)
          a1[mf] = *(const short8*)(smem + abase[mf] + base0 + 4*GSTRIDE);

#pragma unroll
        for (int mf = 0; mf < MF; mf++)
          acc[mf] = __builtin_amdgcn_mfma_f32_16x16x32_bf16(a0[mf], ch0, acc[mf], 0, 0, 0);
#pragma unroll
        for (int mf = 0; mf < MF; mf++)
          acc[mf] = __builtin_amdgcn_mfma_f32_16x16x32_bf16(a0[mf], cm0, acc[mf], 0, 0, 0);
#pragma unroll
        for (int mf = 0; mf < MF; mf++)
          acc[mf] = __builtin_amdgcn_mfma_f32_16x16x32_bf16(a0[mf], cl0, acc[mf], 0, 0, 0);
#pragma unroll
        for (int mf = 0; mf < MF; mf++)
          acc[mf] = __builtin_amdgcn_mfma_f32_16x16x32_bf16(a1[mf], ch1, acc[mf], 0, 0, 0);
#pragma unroll
        for (int mf = 0; mf < MF; mf++)
          acc[mf] = __builtin_amdgcn_mfma_f32_16x16x32_bf16(a1[mf], cm1, acc[mf], 0, 0, 0);
#pragma unroll
        for (int mf = 0; mf < MF; mf++)
          acc[mf] = __builtin_amdgcn_mfma_f32_16x16x32_bf16(a1[mf], cl1, acc[mf], 0, 0, 0);

        ch0 = nh0; cm0 = nm0; cl0 = nl0;
        ch1 = nh1; cm1 = nm1; cl1 = nl1;
        bo = bon;
      }

      if constexpr (HALVES == 1) {
#pragma unroll
        for (int mf = 0; mf < MF; mf++) accsum[mf] = acc[mf];
      } else {
#pragma unroll
        for (int mf = 0; mf < MF; mf++)
#pragma unroll
          for (int r = 0; r < 4; r++) accsum[mf][r] += acc[mf][r];
      }
    }

    // ---- epilogue: C re-tile via LDS -> per-thread LIF on register state ----
    __syncthreads();                     // A-LDS dead; reuse
    float* cb = (float*)smem;
    unsigned short* zb = (unsigned short*)(smem + CBYTES);
    {
      int chn = wn*16 + (lane & 15);
#pragma unroll
      for (int mf = 0; mf < MF; mf++)
#pragma unroll
        for (int r = 0; r < 4; r++) {
          int pix = mf*16 + (lane >> 4)*4 + r;
          cb[pix*BN + (chn ^ ((pix & 3) << 4))] = accsum[mf][r];
        }
    }
    __syncthreads();
#pragma unroll
    for (int k = 0; k < ITER; k++) {
      int e = k*THREADS + tid;
      int row = e >> 4;
      int ch  = (e & 15) << 2;
      f32x4 cv = *(const f32x4*)&cb[row*BN + (ch ^ ((row & 3) << 4))];
      unsigned short zs[4];
#pragma unroll
      for (int s = 0; s < 4; s++) {
        float vdec = vreg[k][s] + DTM*((0.0f - vreg[k][s]) + ireg[k][s]);
        bool z = (vdec - VTH) > 0.0f;
        vreg[k][s] = z ? 0.0f : vdec;
        ireg[k][s] = SYN*ireg[k][s] + cv[s];
        zs[s] = z ? 0x3F80 : 0;
      }
      *(ushort4*)&zb[row*BN + ch] = make_ushort4(zs[0],zs[1],zs[2],zs[3]);
    }

    __syncthreads();
    unsigned short* zpool = zpool_all + (long)t*ZDST_STEP;
    constexpr int WP = WI/2, PR = ROWS/2, CH16 = BN/8;
    for (int c = tid; c < PR*WP*CH16; c += THREADS) {
      int ppx = c / CH16, ck = c % CH16;
      int py = ppx / WP, px = ppx % WP;
      int b0_ = ((2*py)*WI + 2*px)*BN + ck*8;
      u32x4 q0 = *(const u32x4*)(zb + b0_);
      u32x4 q1 = *(const u32x4*)(zb + b0_ + BN);
      u32x4 q2 = *(const u32x4*)(zb + b0_ + WI*BN);
      u32x4 q3 = *(const u32x4*)(zb + b0_ + WI*BN + BN);
      u32x4 vo = (q0|q1)|(q2|q3);
      long g = ((long)(b*(HIM/2) + (y0>>1) + py)*WP + px)*COUT + nt*BN + ck*8;
      *(u32x4*)(zpool + g) = vo;
    }
  }
}

// ---------------------------------------------------------------------------
// K5: FC(4096->10) over pooled L4 spikes + LI + noise + running max, all 16
// timesteps in-kernel, LI state in registers. 32 blocks x 512 threads.
// ---------------------------------------------------------------------------
__global__ __launch_bounds__(512) void k5_time(
    const unsigned short* __restrict__ z4p_all, const float* __restrict__ wfc,
    const float* __restrict__ noise, float* __restrict__ dout)
{
  __shared__ float red[8][10];
  int tid = threadIdx.x, b = blockIdx.x;
  float vo = 0.f, io = 0.f, mx = 0.f;

  for (int t = 0; t < 16; t++) {
    __syncthreads();                     // red free of previous step
    const unsigned short* z4p = z4p_all + (long)t*131072;
    float sums[10];
#pragma unroll
    for (int j = 0; j < 10; j++) sums[j] = 0.f;
#pragma unroll
    for (int q = 0; q < 8; q++) {
      int k = q*512 + tid;
      int c = k >> 4, s = k & 15, py = s >> 2, px = s & 3;
      float zf = bf2f(z4p[((b*4 + py)*4 + px)*256 + c]);
#pragma unroll
      for (int j = 0; j < 10; j++)
        sums[j] = fmaf(zf, wfc[j*4096 + k], sums[j]);
    }
#pragma unroll
    for (int j = 0; j < 10; j++) {
      float v = sums[j];
      for (int off = 32; off; off >>= 1) v += __shfl_xor(v, off);
      if ((tid & 63) == 0) red[tid >> 6][j] = v;
    }
    __syncthreads();
    if (tid < 10) {
      float o = 0.f;
#pragma unroll
      for (int w = 0; w < 8; w++) o += red[w][tid];
      float vn = vo + DTM*((0.0f - vo) + io);
      float inw = SYN*io + o;
      vo = vn; io = inw;
      float volt = vn + 0.001f*noise[((long)t*32 + b)*10 + tid];
      mx = (t == 0) ? volt : fmaxf(mx, volt);
    }
  }
  if (tid < 10) dout[b*10 + tid] = mx;
}

// ---------------------------------------------------------------------------
extern "C" void kernel_launch(void* const* d_in, const int* in_sizes, int n_in,
                              void* d_out, int out_size, void* d_ws, size_t ws_size,
                              hipStream_t stream)
{
  const float* x     = (const float*)d_in[0];
  const float* noise = (const float*)d_in[1];
  const float* w1    = (const float*)d_in[2];
  const float* w2    = (const float*)d_in[3];
  const float* w3    = (const float*)d_in[4];
  const float* w4    = (const float*)d_in[5];
  const float* wfc   = (const float*)d_in[6];
  float* dout = (float*)d_out;

  char* ws = (char*)d_ws;
  size_t off = 0;
  auto alloc = [&](size_t bytes) -> char* {
    char* p = ws + off;
    off = (off + bytes + 255) & ~(size_t)255;
    return p;
  };
  unsigned short* z1  = (unsigned short*)alloc(16u*2097152u*2);  // [16][32][32][32][64]
  unsigned short* z2p = (unsigned short*)alloc(16u*1048576u*2);  // [16][32][16][16][128]
  unsigned short* z3p = (unsigned short*)alloc(16u*524288u*2);   // [16][32][8][8][256]
  unsigned short* z4p = (unsigned short*)alloc(16u*131072u*2);   // [16][32][4][4][256]
  unsigned short* wb2h = (unsigned short*)alloc(73728u*2);
  unsigned short* wb2m = (unsigned short*)alloc(73728u*2);
  unsigned short* wb2l = (unsigned short*)alloc(73728u*2);
  unsigned short* wb3h = (unsigned short*)alloc(294912u*2);
  unsigned short* wb3m = (unsigned short*)alloc(294912u*2);
  unsigned short* wb3l = (unsigned short*)alloc(294912u*2);
  unsigned short* wb4h = (unsigned short*)alloc(589824u*2);
  unsigned short* wb4m = (unsigned short*)alloc(589824u*2);
  unsigned short* wb4l = (unsigned short*)alloc(589824u*2);

  prep_kernel<<<3744, 256, 0, stream>>>(w2, w3, w4,
      wb2h, wb2m, wb2l, wb3h, wb3m, wb3l, wb4h, wb4m, wb4l);

  // L1: conv1+LIF1, all t (state in regs), grid 512
  k1_time<<<512, 256, 0, stream>>>(x, w1, z1);
  // L2: 64->128 @32x32, BM=64 BN=64 NT=2, all t, grid 1024
  conv_time<4, 64,1,32,32,128, 64,2,2097152,1048576><<<1024, 256, 0, stream>>>(
      z1, wb2h, wb2m, wb2l, z2p);
  // L3: 128->256 @16x16 pooled-in, BM=32 BN=64 NT=4, all t, grid 1024
  conv_time<2,128,1,16,16,256,128,4,1048576,524288><<<1024, 256, 0, stream>>>(
      z2p, wb3h, wb3m, wb3l, z3p);
  // L4: 256->256 @8x8 pooled-in, FULL K (2 halves), BM=16 NT=4, all t, grid 512
  conv_time<1,256,2, 8, 8,256,256,4,524288,131072><<<512, 256, 0, stream>>>(
      z3p, wb4h, wb4m, wb4l, z4p);
  // FC + LI + max, all t, grid 32
  k5_time<<<32, 512, 0, stream>>>(z4p, wfc, noise, dout);
}

// Round 16
// 915.056 us; speedup vs baseline: 2.9151x; 1.0739x over previous
//
#include <hip/hip_runtime.h>

typedef __attribute__((ext_vector_type(8))) short short8;
typedef __attribute__((ext_vector_type(4))) float f32x4;
typedef __attribute__((ext_vector_type(4))) unsigned int u32x4;

#define DEV static __device__ __forceinline__

DEV unsigned short f2bf(float f){
  unsigned int u = __float_as_uint(f);
  u += 0x7FFFu + ((u >> 16) & 1u);
  return (unsigned short)(u >> 16);
}
DEV float bf2f(unsigned short h){ return __uint_as_float(((unsigned int)h) << 16); }

#define DTM 0.1f   /* DT*TAU_MEM_INV */
#define SYN 0.8f   /* 1 - DT*TAU_SYN_INV */
#define VTH 0.2f

// ---------------------------------------------------------------------------
// prep: weights -> MFMA-fragment-major bf16 hi/mid/lo digit layout (as r12).
// ---------------------------------------------------------------------------
__global__ __launch_bounds__(256) void prep_kernel(
    const float* __restrict__ w2, const float* __restrict__ w3, const float* __restrict__ w4,
    unsigned short* __restrict__ wb2h, unsigned short* __restrict__ wb2m, unsigned short* __restrict__ wb2l,
    unsigned short* __restrict__ wb3h, unsigned short* __restrict__ wb3m, unsigned short* __restrict__ wb3l,
    unsigned short* __restrict__ wb4h, unsigned short* __restrict__ wb4m, unsigned short* __restrict__ wb4l)
{
  const int N2 = 9*128*64, N3 = 9*256*128, N4 = 9*256*256;
  int tid = blockIdx.x*256 + threadIdx.x;
  if (tid < N2) {
    int j = tid & 7, co = (tid >> 3) & 127, q = (tid >> 3) >> 7;
    int kg = q & 3, sg = q >> 2;
    int tap = sg >> 1, ks = sg & 1;
    int ci = ks*32 + kg*8 + j;
    float w = w2[(co*64 + ci)*9 + tap];
    unsigned short h = f2bf(w);   float r1 = w - bf2f(h);
    unsigned short m = f2bf(r1);  float r2 = r1 - bf2f(m);
    wb2h[tid] = h; wb2m[tid] = m; wb2l[tid] = f2bf(r2);
    return;
  }
  tid -= N2;
  if (tid < N3) {
    int j = tid & 7, co = (tid >> 3) & 255, q = (tid >> 3) >> 8;
    int kg = q & 3, sg = q >> 2;
    int p = sg >> 1, ks = sg & 1, tap = p >> 1, cs = p & 1;
    int ci = cs*64 + ks*32 + kg*8 + j;
    float w = w3[(co*128 + ci)*9 + tap];
    unsigned short h = f2bf(w);   float r1 = w - bf2f(h);
    unsigned short m = f2bf(r1);  float r2 = r1 - bf2f(m);
    wb3h[tid] = h; wb3m[tid] = m; wb3l[tid] = f2bf(r2);
    return;
  }
  tid -= N3;
  if (tid < N4) {
    int j = tid & 7, co = (tid >> 3) & 255, q = (tid >> 3) >> 8;
    int kg = q & 3, sg = q >> 2;
    int hh = sg / 36, sl = sg % 36;
    int p = sl >> 1, ks = sl & 1, tap = p >> 1, cs = p & 1;
    int ci = hh*128 + cs*64 + ks*32 + kg*8 + j;
    float w = w4[(co*256 + ci)*9 + tap];
    unsigned short h = f2bf(w);   float r1 = w - bf2f(h);
    unsigned short m = f2bf(r1);  float r2 = r1 - bf2f(m);
    wb4h[tid] = h; wb4m[tid] = m; wb4l[tid] = f2bf(r2);
  }
}

// ---------------------------------------------------------------------------
// K1: conv1 (fp32 direct, 3->64) + LIF1, ALL 16 timesteps in-kernel, state in
// registers. grid 512 = 32 imgs x 16 row-pairs.
// ---------------------------------------------------------------------------
__global__ __launch_bounds__(256, 4) void k1_time(
    const float* __restrict__ x, const float* __restrict__ w1,
    unsigned short* __restrict__ z1_all)
{
  __shared__ float xs[3][4][34];
  __shared__ float wl[27][64];
  int tid = threadIdx.x;
  int b = blockIdx.x >> 4, y0 = (blockIdx.x & 15) * 2;
  for (int e = tid; e < 27*64; e += 256) {
    int row = e >> 6, co = e & 63;
    int ci = row % 3, tap = row / 3, ky = tap/3, kx = tap%3;
    wl[row][co] = w1[((co*3+ci)*3+ky)*3+kx];
  }
  int px = tid >> 2, cg = tid & 3;
  int ly = px >> 5, lx = px & 31;
  int m_g = b*1024 + (y0+ly)*32 + lx;

  float vv[16], ii[16];
#pragma unroll
  for (int q = 0; q < 16; q++) { vv[q] = 0.f; ii[q] = 0.f; }

  for (int t = 0; t < 16; t++) {
    __syncthreads();
    for (int e = tid; e < 3*4*34; e += 256) {
      int ci = e/136, r2 = e%136, r = r2/34, xi = r2%34;
      int y = y0 - 1 + r, xg = xi - 1;
      float v = 0.f;
      if (y >= 0 && y < 32 && xg >= 0 && xg < 32)
        v = x[((t*32 + b)*3 + ci)*1024 + y*32 + xg];
      xs[ci][r][xi] = v;
    }
    __syncthreads();
    float acc[16];
#pragma unroll
    for (int q = 0; q < 16; q++) acc[q] = 0.f;
#pragma unroll
    for (int ky = 0; ky < 3; ky++)
#pragma unroll
      for (int kx = 0; kx < 3; kx++)
#pragma unroll
        for (int ci = 0; ci < 3; ci++) {
          float xv = xs[ci][ly+ky][lx+kx];
          const float4* wr = (const float4*)&wl[(ky*3+kx)*3+ci][cg*16];
#pragma unroll
          for (int q = 0; q < 4; q++) {
            float4 w4 = wr[q];
            acc[q*4+0] = fmaf(xv, w4.x, acc[q*4+0]);
            acc[q*4+1] = fmaf(xv, w4.y, acc[q*4+1]);
            acc[q*4+2] = fmaf(xv, w4.z, acc[q*4+2]);
            acc[q*4+3] = fmaf(xv, w4.w, acc[q*4+3]);
          }
        }
    unsigned short zb[16];
#pragma unroll
    for (int q = 0; q < 16; q++) {
      float vdec = vv[q] + DTM*((0.0f - vv[q]) + ii[q]);
      bool z = (vdec - VTH) > 0.0f;
      vv[q] = z ? 0.0f : vdec;
      ii[q] = SYN*ii[q] + acc[q];
      zb[q] = z ? 0x3F80 : 0;
    }
    unsigned short* z1 = z1_all + (long)t*2097152;
    u32x4 za, zc;
    za[0]=zb[0]|((unsigned)zb[1]<<16); za[1]=zb[2]|((unsigned)zb[3]<<16);
    za[2]=zb[4]|((unsigned)zb[5]<<16); za[3]=zb[6]|((unsigned)zb[7]<<16);
    zc[0]=zb[8]|((unsigned)zb[9]<<16); zc[1]=zb[10]|((unsigned)zb[11]<<16);
    zc[2]=zb[12]|((unsigned)zb[13]<<16); zc[3]=zb[14]|((unsigned)zb[15]<<16);
    *(u32x4*)(z1 + m_g*64 + cg*16) = za;
    *(u32x4*)(z1 + m_g*64 + cg*16 + 8) = zc;
  }
}

// ---------------------------------------------------------------------------
// Time-looped implicit-GEMM conv, TB timesteps batched per K-pass: one B
// fragment load feeds TB timesteps' MFMAs -> B L2 traffic / TB. LIF state in
// registers (zero state HBM traffic). A[TB] tiles staged in LDS per outer
// iteration; epilogue per tb: LDS C re-tile -> reg-state LIF -> 2x2 pool(OR).
// HALVES=2: full K as two sequential half-K accumulators summed at the end.
// Accumulation order per accumulator identical to r15 (bit-exact).
// ---------------------------------------------------------------------------
template<int MF, int CIN_A, int HALVES, int TB, int WI, int HIM, int COUT,
         int CIN_SRC, int NT, int ZSRC_STEP, int ZDST_STEP>
__global__ __launch_bounds__(256, 3) void conv_time(
    const unsigned short* __restrict__ zsrc_all,
    const unsigned short* __restrict__ wbh, const unsigned short* __restrict__ wbm,
    const unsigned short* __restrict__ wbl,
    unsigned short* __restrict__ zpool_all)
{
  constexpr int THREADS = 256;
  constexpr int BM = MF*16;
  constexpr int BN = 64;
  constexpr int ROWS = BM/WI;
  constexpr int SLOTW = WI+2;
  constexpr int SLOTS = (ROWS+2)*SLOTW;
  constexpr int KHALF = CIN_A/HALVES;
  constexpr int CPH = KHALF/64;
  constexpr int NSC = 9*CPH;
  constexpr int MT_PER_B = (HIM*WI)/BM;
  constexpr int ACH = CIN_A/8;
  constexpr int ACHUNKS = SLOTS*ACH;
  constexpr int GSTRIDE = (SLOTS+1)*16;
  constexpr int ABYTES = ACH*GSTRIDE;
  constexpr int CBYTES = BM*BN*4;
  constexpr int EBYTES = CBYTES + BM*BN*2;
  constexpr int LDSB = (TB*ABYTES > EBYTES) ? TB*ABYTES : EBYTES;
  constexpr int ITER = (BM*BN/4)/THREADS;
  static_assert(LDSB <= 64*1024, "LDS");

  __shared__ __align__(16) char smem[LDSB];

  int tid = threadIdx.x;
  int rem = blockIdx.x;
  int nt = 0;
  if constexpr (NT > 1) { nt = rem % NT; rem /= NT; }
  int b = rem / MT_PER_B;
  int y0 = (rem % MT_PER_B) * ROWS;
  int lane = tid & 63, wn = tid >> 6;
  int kg = lane >> 4;

  int abase[MF];
#pragma unroll
  for (int mf = 0; mf < MF; mf++) {
    int pl = mf*16 + (lane & 15);
    int yl = pl / WI, xl = pl % WI;
    abase[mf] = kg*GSTRIDE + (yl*SLOTW + xl)*16;
  }

  int co_g = nt*BN + wn*16 + (lane & 15);
  const long bstep = (long)4*COUT*8;
  const long blane = ((long)kg*COUT + co_g)*8;

  // LIF state in registers (statically indexed); t=0 starts from zeros.
  f32x4 vreg[ITER], ireg[ITER];
#pragma unroll
  for (int k = 0; k < ITER; k++) {
    vreg[k][0]=0.f; vreg[k][1]=0.f; vreg[k][2]=0.f; vreg[k][3]=0.f;
    ireg[k][0]=0.f; ireg[k][1]=0.f; ireg[k][2]=0.f; ireg[k][3]=0.f;
  }

  for (int t0 = 0; t0 < 16; t0 += TB) {
    __syncthreads();                     // smem free of previous epilogue
    // ---- stage A tiles for TB timesteps ----
#pragma unroll
    for (int tb = 0; tb < TB; tb++) {
      const unsigned short* zsrc = zsrc_all + (long)(t0 + tb)*ZSRC_STEP;
      char* sm = smem + tb*ABYTES;
      for (int ch = tid; ch < ACHUNKS; ch += THREADS) {
        int slot = ch / ACH, g = ch % ACH;
        int yr = slot / SLOTW, xr = slot % SLOTW;
        int y = y0 + yr - 1, xg = xr - 1;
        u32x4 val; val[0]=0; val[1]=0; val[2]=0; val[3]=0;
        if (y >= 0 && y < HIM && xg >= 0 && xg < WI)
          val = *(const u32x4*)(zsrc + ((long)(b*HIM + y)*WI + xg)*CIN_SRC + g*8);
        *(u32x4*)(sm + g*GSTRIDE + slot*16) = val;
      }
    }
    __syncthreads();

    f32x4 accsum[TB][MF];
#pragma unroll
    for (int tb = 0; tb < TB; tb++)
#pragma unroll
      for (int mf = 0; mf < MF; mf++) {
        accsum[tb][mf][0]=0.f; accsum[tb][mf][1]=0.f;
        accsum[tb][mf][2]=0.f; accsum[tb][mf][3]=0.f;
      }

#pragma unroll
    for (int hh = 0; hh < HALVES; hh++) {
      f32x4 acc[TB][MF];
#pragma unroll
      for (int tb = 0; tb < TB; tb++)
#pragma unroll
        for (int mf = 0; mf < MF; mf++) {
          acc[tb][mf][0]=0.f; acc[tb][mf][1]=0.f;
          acc[tb][mf][2]=0.f; acc[tb][mf][3]=0.f;
        }
      long bo = blane + (long)(hh*NSC*2)*bstep;
      short8 ch0 = *(const short8*)(wbh + bo);
      short8 cm0 = *(const short8*)(wbm + bo);
      short8 cl0 = *(const short8*)(wbl + bo);
      short8 ch1 = *(const short8*)(wbh + bo + bstep);
      short8 cm1 = *(const short8*)(wbm + bo + bstep);
      short8 cl1 = *(const short8*)(wbl + bo + bstep);

#pragma unroll 1
      for (int sc = 0; sc < NSC; sc++) {
        long bon = bo + ((sc + 1 < NSC) ? 2*bstep : 0);
        short8 nh0 = *(const short8*)(wbh + bon);
        short8 nm0 = *(const short8*)(wbm + bon);
        short8 nl0 = *(const short8*)(wbl + bon);
        short8 nh1 = *(const short8*)(wbh + bon + bstep);
        short8 nm1 = *(const short8*)(wbm + bon + bstep);
        short8 nl1 = *(const short8*)(wbl + bon + bstep);

        int tap, cs;
        if constexpr (CPH == 1) { tap = sc; cs = 0; }
        else { tap = sc >> 1; cs = sc & 1; }
        int ty = (tap*171) >> 9;
        int tx = tap - ty*3;
        int base0 = (hh*(KHALF/8) + cs*8)*GSTRIDE + (ty*SLOTW + tx)*16;

#pragma unroll
        for (int tb = 0; tb < TB; tb++) {
          const char* sm = smem + tb*ABYTES;
          short8 a0[MF], a1[MF];
#pragma unroll
          for (int mf = 0; mf < MF; mf++)
            a0[mf] = *(const short8*)(sm + abase[mf] + base0);
#pragma unroll
          for (int mf = 0; mf < MF; mf++)
            a1[mf] = *(const short8*)(sm + abase[mf] + base0 + 4*GSTRIDE);
#pragma unroll
          for (int mf = 0; mf < MF; mf++)
            acc[tb][mf] = __builtin_amdgcn_mfma_f32_16x16x32_bf16(a0[mf], ch0, acc[tb][mf], 0, 0, 0);
#pragma unroll
          for (int mf = 0; mf < MF; mf++)
            acc[tb][mf] = __builtin_amdgcn_mfma_f32_16x16x32_bf16(a0[mf], cm0, acc[tb][mf], 0, 0, 0);
#pragma unroll
          for (int mf = 0; mf < MF; mf++)
            acc[tb][mf] = __builtin_amdgcn_mfma_f32_16x16x32_bf16(a0[mf], cl0, acc[tb][mf], 0, 0, 0);
#pragma unroll
          for (int mf = 0; mf < MF; mf++)
            acc[tb][mf] = __builtin_amdgcn_mfma_f32_16x16x32_bf16(a1[mf], ch1, acc[tb][mf], 0, 0, 0);
#pragma unroll
          for (int mf = 0; mf < MF; mf++)
            acc[tb][mf] = __builtin_amdgcn_mfma_f32_16x16x32_bf16(a1[mf], cm1, acc[tb][mf], 0, 0, 0);
#pragma unroll
          for (int mf = 0; mf < MF; mf++)
            acc[tb][mf] = __builtin_amdgcn_mfma_f32_16x16x32_bf16(a1[mf], cl1, acc[tb][mf], 0, 0, 0);
        }

        ch0 = nh0; cm0 = nm0; cl0 = nl0;
        ch1 = nh1; cm1 = nm1; cl1 = nl1;
        bo = bon;
      }

      if constexpr (HALVES == 1) {
#pragma unroll
        for (int tb = 0; tb < TB; tb++)
#pragma unroll
          for (int mf = 0; mf < MF; mf++) accsum[tb][mf] = acc[tb][mf];
      } else {
#pragma unroll
        for (int tb = 0; tb < TB; tb++)
#pragma unroll
          for (int mf = 0; mf < MF; mf++)
#pragma unroll
            for (int r = 0; r < 4; r++) accsum[tb][mf][r] += acc[tb][mf][r];
      }
    }

    // ---- epilogues: per tb, C re-tile via LDS -> reg-state LIF -> pool ----
#pragma unroll
    for (int tb = 0; tb < TB; tb++) {
      __syncthreads();                   // A-LDS / previous tb's zb dead
      float* cb = (float*)smem;
      unsigned short* zb = (unsigned short*)(smem + CBYTES);
      {
        int chn = wn*16 + (lane & 15);
#pragma unroll
        for (int mf = 0; mf < MF; mf++)
#pragma unroll
          for (int r = 0; r < 4; r++) {
            int pix = mf*16 + (lane >> 4)*4 + r;
            cb[pix*BN + (chn ^ ((pix & 3) << 4))] = accsum[tb][mf][r];
          }
      }
      __syncthreads();
#pragma unroll
      for (int k = 0; k < ITER; k++) {
        int e = k*THREADS + tid;
        int row = e >> 4;
        int ch  = (e & 15) << 2;
        f32x4 cv = *(const f32x4*)&cb[row*BN + (ch ^ ((row & 3) << 4))];
        unsigned short zs[4];
#pragma unroll
        for (int s = 0; s < 4; s++) {
          float vdec = vreg[k][s] + DTM*((0.0f - vreg[k][s]) + ireg[k][s]);
          bool z = (vdec - VTH) > 0.0f;
          vreg[k][s] = z ? 0.0f : vdec;
          ireg[k][s] = SYN*ireg[k][s] + cv[s];
          zs[s] = z ? 0x3F80 : 0;
        }
        *(ushort4*)&zb[row*BN + ch] = make_ushort4(zs[0],zs[1],zs[2],zs[3]);
      }
      __syncthreads();
      unsigned short* zpool = zpool_all + (long)(t0 + tb)*ZDST_STEP;
      constexpr int WP = WI/2, PR = ROWS/2, CH16 = BN/8;
      for (int c = tid; c < PR*WP*CH16; c += THREADS) {
        int ppx = c / CH16, ck = c % CH16;
        int py = ppx / WP, px = ppx % WP;
        int b0_ = ((2*py)*WI + 2*px)*BN + ck*8;
        u32x4 q0 = *(const u32x4*)(zb + b0_);
        u32x4 q1 = *(const u32x4*)(zb + b0_ + BN);
        u32x4 q2 = *(const u32x4*)(zb + b0_ + WI*BN);
        u32x4 q3 = *(const u32x4*)(zb + b0_ + WI*BN + BN);
        u32x4 vo = (q0|q1)|(q2|q3);
        long g = ((long)(b*(HIM/2) + (y0>>1) + py)*WP + px)*COUT + nt*BN + ck*8;
        *(u32x4*)(zpool + g) = vo;
      }
    }
  }
}

// ---------------------------------------------------------------------------
// K5: FC(4096->10) over pooled L4 spikes + LI + noise + running max, all 16
// timesteps in-kernel, LI state in registers. 32 blocks x 512 threads.
// ---------------------------------------------------------------------------
__global__ __launch_bounds__(512) void k5_time(
    const unsigned short* __restrict__ z4p_all, const float* __restrict__ wfc,
    const float* __restrict__ noise, float* __restrict__ dout)
{
  __shared__ float red[8][10];
  int tid = threadIdx.x, b = blockIdx.x;
  float vo = 0.f, io = 0.f, mx = 0.f;

  for (int t = 0; t < 16; t++) {
    __syncthreads();
    const unsigned short* z4p = z4p_all + (long)t*131072;
    float sums[10];
#pragma unroll
    for (int j = 0; j < 10; j++) sums[j] = 0.f;
#pragma unroll
    for (int q = 0; q < 8; q++) {
      int k = q*512 + tid;
      int c = k >> 4, s = k & 15, py = s >> 2, px = s & 3;
      float zf = bf2f(z4p[((b*4 + py)*4 + px)*256 + c]);
#pragma unroll
      for (int j = 0; j < 10; j++)
        sums[j] = fmaf(zf, wfc[j*4096 + k], sums[j]);
    }
#pragma unroll
    for (int j = 0; j < 10; j++) {
      float v = sums[j];
      for (int off = 32; off; off >>= 1) v += __shfl_xor(v, off);
      if ((tid & 63) == 0) red[tid >> 6][j] = v;
    }
    __syncthreads();
    if (tid < 10) {
      float o = 0.f;
#pragma unroll
      for (int w = 0; w < 8; w++) o += red[w][tid];
      float vn = vo + DTM*((0.0f - vo) + io);
      float inw = SYN*io + o;
      vo = vn; io = inw;
      float volt = vn + 0.001f*noise[((long)t*32 + b)*10 + tid];
      mx = (t == 0) ? volt : fmaxf(mx, volt);
    }
  }
  if (tid < 10) dout[b*10 + tid] = mx;
}

// ---------------------------------------------------------------------------
extern "C" void kernel_launch(void* const* d_in, const int* in_sizes, int n_in,
                              void* d_out, int out_size, void* d_ws, size_t ws_size,
                              hipStream_t stream)
{
  const float* x     = (const float*)d_in[0];
  const float* noise = (const float*)d_in[1];
  const float* w1    = (const float*)d_in[2];
  const float* w2    = (const float*)d_in[3];
  const float* w3    = (const float*)d_in[4];
  const float* w4    = (const float*)d_in[5];
  const float* wfc   = (const float*)d_in[6];
  float* dout = (float*)d_out;

  char* ws = (char*)d_ws;
  size_t off = 0;
  auto alloc = [&](size_t bytes) -> char* {
    char* p = ws + off;
    off = (off + bytes + 255) & ~(size_t)255;
    return p;
  };
  unsigned short* z1  = (unsigned short*)alloc(16u*2097152u*2);  // [16][32][32][32][64]
  unsigned short* z2p = (unsigned short*)alloc(16u*1048576u*2);  // [16][32][16][16][128]
  unsigned short* z3p = (unsigned short*)alloc(16u*524288u*2);   // [16][32][8][8][256]
  unsigned short* z4p = (unsigned short*)alloc(16u*131072u*2);   // [16][32][4][4][256]
  unsigned short* wb2h = (unsigned short*)alloc(73728u*2);
  unsigned short* wb2m = (unsigned short*)alloc(73728u*2);
  unsigned short* wb2l = (unsigned short*)alloc(73728u*2);
  unsigned short* wb3h = (unsigned short*)alloc(294912u*2);
  unsigned short* wb3m = (unsigned short*)alloc(294912u*2);
  unsigned short* wb3l = (unsigned short*)alloc(294912u*2);
  unsigned short* wb4h = (unsigned short*)alloc(589824u*2);
  unsigned short* wb4m = (unsigned short*)alloc(589824u*2);
  unsigned short* wb4l = (unsigned short*)alloc(589824u*2);

  prep_kernel<<<3744, 256, 0, stream>>>(w2, w3, w4,
      wb2h, wb2m, wb2l, wb3h, wb3m, wb3l, wb4h, wb4m, wb4l);

  // L1: conv1+LIF1, all t (state in regs), grid 512
  k1_time<<<512, 256, 0, stream>>>(x, w1, z1);
  // L2: 64->128 @32x32, BM=64 BN=64 NT=2, TB=2, grid 1024 (LDS 35KB)
  conv_time<4, 64,1,2,32,32,128, 64,2,2097152,1048576><<<1024, 256, 0, stream>>>(
      z1, wb2h, wb2m, wb2l, z2p);
  // L3: 128->256 @16x16 pooled-in, BM=32 BN=64 NT=4, TB=2, grid 1024 (LDS 37KB)
  conv_time<2,128,1,2,16,16,256,128,4,1048576,524288><<<1024, 256, 0, stream>>>(
      z2p, wb3h, wb3m, wb3l, z3p);
  // L4: 256->256 @8x8 pooled-in, FULL K (2 halves), BM=16 NT=4, TB=2, grid 512 (LDS 42KB)
  conv_time<1,256,2,2, 8, 8,256,256,4,524288,131072><<<512, 256, 0, stream>>>(
      z3p, wb4h, wb4m, wb4l, z4p);
  // FC + LI + max, all t, grid 32
  k5_time<<<32, 512, 0, stream>>>(z4p, wfc, noise, dout);
}

// Round 17
// 564.055 us; speedup vs baseline: 4.7291x; 1.6223x over previous
//
#include <hip/hip_runtime.h>

typedef __attribute__((ext_vector_type(4))) int i32x4;
typedef __attribute__((ext_vector_type(4))) float f32x4;
typedef __attribute__((ext_vector_type(4))) unsigned int u32x4;

#define DEV static __device__ __forceinline__

#define DTM 0.1f   /* DT*TAU_MEM_INV */
#define SYN 0.8f   /* 1 - DT*TAU_SYN_INV */
#define VTH 0.2f

// ---------------------------------------------------------------------------
// 4-digit balanced base-256 i8 decomposition of round(w * 2^30).
// w == (d3*2^24 + d2*2^16 + d1*2^8 + d0) * 2^-30 up to 2^-31 quantization.
// ---------------------------------------------------------------------------
DEV void dec4(float w, signed char d[4]) {
  int I = (int)rintf(w * 1073741824.0f);       // |I| < 2^29 for he-init weights
  int d0 = ((I + 128) & 255) - 128; I = (I - d0) >> 8;
  int d1 = ((I + 128) & 255) - 128; I = (I - d1) >> 8;
  int d2 = ((I + 128) & 255) - 128; I = (I - d2) >> 8;
  d[0] = (signed char)d0; d[1] = (signed char)d1;
  d[2] = (signed char)d2; d[3] = (signed char)I;
}

// ---------------------------------------------------------------------------
// prep: weights -> i8 digit fragments, MFMA-fragment-major K=64 layout:
//   wbX_d[((sg*4 + kg)*COUT + co)*16 + j] = digit_d(w[co][ci(sg,kg,j)][tap(sg)])
// (flat tid == destination index for all three layers by construction)
// ---------------------------------------------------------------------------
__global__ __launch_bounds__(256) void prep_kernel(
    const float* __restrict__ w2, const float* __restrict__ w3, const float* __restrict__ w4,
    signed char* __restrict__ b2_0, signed char* __restrict__ b2_1,
    signed char* __restrict__ b2_2, signed char* __restrict__ b2_3,
    signed char* __restrict__ b3_0, signed char* __restrict__ b3_1,
    signed char* __restrict__ b3_2, signed char* __restrict__ b3_3,
    signed char* __restrict__ b4_0, signed char* __restrict__ b4_1,
    signed char* __restrict__ b4_2, signed char* __restrict__ b4_3)
{
  const int N2 = 9*128*64, N3 = 9*256*128, N4 = 9*256*256;
  int tid = blockIdx.x*256 + threadIdx.x;
  signed char d[4];
  if (tid < N2) {           // conv2: CIN=64, sg in [0,9)
    int j = tid & 15, co = (tid >> 4) & 127, q = tid >> 11;
    int kg = q & 3, sg = q >> 2;
    int ci = kg*16 + j;
    dec4(w2[(co*64 + ci)*9 + sg], d);
    b2_0[tid] = d[0]; b2_1[tid] = d[1]; b2_2[tid] = d[2]; b2_3[tid] = d[3];
    return;
  }
  tid -= N2;
  if (tid < N3) {           // conv3: CIN=128, sg in [0,18)
    int j = tid & 15, co = (tid >> 4) & 255, q = tid >> 12;
    int kg = q & 3, sg = q >> 2;
    int tap = sg >> 1, cs = sg & 1;
    int ci = cs*64 + kg*16 + j;
    dec4(w3[(co*128 + ci)*9 + tap], d);
    b3_0[tid] = d[0]; b3_1[tid] = d[1]; b3_2[tid] = d[2]; b3_3[tid] = d[3];
    return;
  }
  tid -= N3;
  if (tid < N4) {           // conv4: CIN=256, sg in [0,36)
    int j = tid & 15, co = (tid >> 4) & 255, q = tid >> 12;
    int kg = q & 3, sg = q >> 2;
    int tap = sg >> 2, cs = sg & 3;
    int ci = cs*64 + kg*16 + j;
    dec4(w4[(co*256 + ci)*9 + tap], d);
    b4_0[tid] = d[0]; b4_1[tid] = d[1]; b4_2[tid] = d[2]; b4_3[tid] = d[3];
  }
}

// ---------------------------------------------------------------------------
// K1: conv1 (fp32 direct, 3->64) + LIF1, all 16 timesteps in-kernel, state in
// registers. grid 512 = 32 imgs x 16 row-pairs. Spikes written as i8 {0,1}.
// ---------------------------------------------------------------------------
__global__ __launch_bounds__(256, 4) void k1_time(
    const float* __restrict__ x, const float* __restrict__ w1,
    unsigned char* __restrict__ z1_all)
{
  __shared__ float xs[3][4][34];
  __shared__ float wl[27][64];
  int tid = threadIdx.x;
  int b = blockIdx.x >> 4, y0 = (blockIdx.x & 15) * 2;
  for (int e = tid; e < 27*64; e += 256) {
    int row = e >> 6, co = e & 63;
    int ci = row % 3, tap = row / 3, ky = tap/3, kx = tap%3;
    wl[row][co] = w1[((co*3+ci)*3+ky)*3+kx];
  }
  int px = tid >> 2, cg = tid & 3;
  int ly = px >> 5, lx = px & 31;
  int m_g = b*1024 + (y0+ly)*32 + lx;

  float vv[16], ii[16];
#pragma unroll
  for (int q = 0; q < 16; q++) { vv[q] = 0.f; ii[q] = 0.f; }

  for (int t = 0; t < 16; t++) {
    __syncthreads();
    for (int e = tid; e < 3*4*34; e += 256) {
      int ci = e/136, r2 = e%136, r = r2/34, xi = r2%34;
      int y = y0 - 1 + r, xg = xi - 1;
      float v = 0.f;
      if (y >= 0 && y < 32 && xg >= 0 && xg < 32)
        v = x[((t*32 + b)*3 + ci)*1024 + y*32 + xg];
      xs[ci][r][xi] = v;
    }
    __syncthreads();
    float acc[16];
#pragma unroll
    for (int q = 0; q < 16; q++) acc[q] = 0.f;
#pragma unroll
    for (int ky = 0; ky < 3; ky++)
#pragma unroll
      for (int kx = 0; kx < 3; kx++)
#pragma unroll
        for (int ci = 0; ci < 3; ci++) {
          float xv = xs[ci][ly+ky][lx+kx];
          const float4* wr = (const float4*)&wl[(ky*3+kx)*3+ci][cg*16];
#pragma unroll
          for (int q = 0; q < 4; q++) {
            float4 w4 = wr[q];
            acc[q*4+0] = fmaf(xv, w4.x, acc[q*4+0]);
            acc[q*4+1] = fmaf(xv, w4.y, acc[q*4+1]);
            acc[q*4+2] = fmaf(xv, w4.z, acc[q*4+2]);
            acc[q*4+3] = fmaf(xv, w4.w, acc[q*4+3]);
          }
        }
    unsigned int zb[16];
#pragma unroll
    for (int q = 0; q < 16; q++) {
      float vdec = vv[q] + DTM*((0.0f - vv[q]) + ii[q]);
      bool z = (vdec - VTH) > 0.0f;
      vv[q] = z ? 0.0f : vdec;
      ii[q] = SYN*ii[q] + acc[q];
      zb[q] = z ? 1u : 0u;
    }
    u32x4 zo;
#pragma unroll
    for (int w = 0; w < 4; w++)
      zo[w] = zb[4*w] | (zb[4*w+1] << 8) | (zb[4*w+2] << 16) | (zb[4*w+3] << 24);
    *(u32x4*)(z1_all + (long)t*2097152 + m_g*64 + cg*16) = zo;
  }
}

// ---------------------------------------------------------------------------
// Time-looped implicit-GEMM conv over i8 spikes, 4 x i8 weight digits,
// mfma_i32_16x16x64_i8 (i32 accumulation is EXACT -> any K order). One A
// ds_read_b128 covers K=64 and feeds 4 digit-MFMAs. TB timesteps batched
// (B fragments amortized). LIF state in registers. Wave-2D (WM x WN) tile.
// Epilogue: double-precision digit combine (correctly-rounded fp32) -> LDS C
// re-tile -> reg-state LIF -> fused 2x2 spike max-pool (byte OR).
// ---------------------------------------------------------------------------
template<int WM, int WN, int MF, int TB, int MINW, int CIN, int WI, int HIM,
         int COUT, int NT, int ZSRC_STEP, int ZDST_STEP>
__global__ __launch_bounds__(256, MINW) void conv_time(
    const unsigned char* __restrict__ zsrc_all,
    const signed char* __restrict__ wd0, const signed char* __restrict__ wd1,
    const signed char* __restrict__ wd2, const signed char* __restrict__ wd3,
    unsigned char* __restrict__ zpool_all)
{
  constexpr int THREADS = 256;
  constexpr int BM = WM*MF*16;
  constexpr int BN = WN*16;
  constexpr int ROWS = BM/WI;
  constexpr int SLOTW = WI+2;
  constexpr int SLOTS = (ROWS+2)*SLOTW;
  constexpr int CPH = CIN/64;
  constexpr int NSC = 9*CPH;
  constexpr int MT_PER_B = (HIM*WI)/BM;
  constexpr int ACH = CIN/16;            // 16-byte channel groups
  constexpr int ACHUNKS = SLOTS*ACH;
  constexpr int GSTRIDE = (SLOTS+1)*16;
  constexpr int ABYTES = ACH*GSTRIDE;
  constexpr int CBYTES = BM*BN*4;
  constexpr int EBYTES = CBYTES + BM*BN;
  constexpr int LDSB = (TB*ABYTES > EBYTES) ? TB*ABYTES : EBYTES;
  constexpr int ITER = (BM*BN/4)/THREADS;
  constexpr int R4 = BN/4;
  static_assert(LDSB <= 64*1024, "LDS");
  static_assert(ROWS >= 2, "pool needs >=2 rows");

  __shared__ __align__(16) char smem[LDSB];

  int tid = threadIdx.x;
  int rem = blockIdx.x;
  int nt = 0;
  if constexpr (NT > 1) { nt = rem % NT; rem /= NT; }
  int b = rem / MT_PER_B;
  int y0 = (rem % MT_PER_B) * ROWS;
  int lane = tid & 63, wv = tid >> 6;
  int wn = wv % WN, wm = wv / WN;
  int kg = lane >> 4;

  int abase[MF];
#pragma unroll
  for (int mf = 0; mf < MF; mf++) {
    int pl = (wm*MF + mf)*16 + (lane & 15);
    int yl = pl / WI, xl = pl % WI;
    abase[mf] = kg*GSTRIDE + (yl*SLOTW + xl)*16;
  }

  int co_g = nt*BN + wn*16 + (lane & 15);
  const long bstep = (long)4*COUT*16;    // bytes per K=64 stage
  const long blane = ((long)kg*COUT + co_g)*16;

  f32x4 vreg[ITER], ireg[ITER];
#pragma unroll
  for (int k = 0; k < ITER; k++) {
    vreg[k][0]=0.f; vreg[k][1]=0.f; vreg[k][2]=0.f; vreg[k][3]=0.f;
    ireg[k][0]=0.f; ireg[k][1]=0.f; ireg[k][2]=0.f; ireg[k][3]=0.f;
  }

  for (int t0 = 0; t0 < 16; t0 += TB) {
    __syncthreads();
    // ---- stage A (i8 spikes) for TB timesteps ----
#pragma unroll
    for (int tb = 0; tb < TB; tb++) {
      const unsigned char* zsrc = zsrc_all + (long)(t0 + tb)*ZSRC_STEP;
      char* sm = smem + tb*ABYTES;
      for (int ch = tid; ch < ACHUNKS; ch += THREADS) {
        int slot = ch / ACH, g = ch % ACH;
        int yr = slot / SLOTW, xr = slot % SLOTW;
        int y = y0 + yr - 1, xg = xr - 1;
        u32x4 val; val[0]=0; val[1]=0; val[2]=0; val[3]=0;
        if (y >= 0 && y < HIM && xg >= 0 && xg < WI)
          val = *(const u32x4*)(zsrc + ((long)(b*HIM + y)*WI + xg)*CIN + g*16);
        *(u32x4*)(sm + g*GSTRIDE + slot*16) = val;
      }
    }
    __syncthreads();

    i32x4 acc[TB][MF][4];
#pragma unroll
    for (int tb = 0; tb < TB; tb++)
#pragma unroll
      for (int mf = 0; mf < MF; mf++)
#pragma unroll
        for (int d = 0; d < 4; d++) {
          acc[tb][mf][d][0]=0; acc[tb][mf][d][1]=0;
          acc[tb][mf][d][2]=0; acc[tb][mf][d][3]=0;
        }

    long bo = blane;
    i32x4 c0 = *(const i32x4*)(wd0 + bo);
    i32x4 c1 = *(const i32x4*)(wd1 + bo);
    i32x4 c2 = *(const i32x4*)(wd2 + bo);
    i32x4 c3 = *(const i32x4*)(wd3 + bo);

#pragma unroll 1
    for (int sc = 0; sc < NSC; sc++) {
      long bon = bo + ((sc + 1 < NSC) ? bstep : 0);
      i32x4 n0 = *(const i32x4*)(wd0 + bon);
      i32x4 n1 = *(const i32x4*)(wd1 + bon);
      i32x4 n2 = *(const i32x4*)(wd2 + bon);
      i32x4 n3 = *(const i32x4*)(wd3 + bon);

      int tap, cs;
      if constexpr (CPH == 1) { tap = sc; cs = 0; }
      else if constexpr (CPH == 2) { tap = sc >> 1; cs = sc & 1; }
      else { tap = sc >> 2; cs = sc & 3; }
      int ty = (tap*171) >> 9;           // tap/3
      int tx = tap - ty*3;               // tap%3
      int base0 = (cs*4)*GSTRIDE + (ty*SLOTW + tx)*16;

#pragma unroll
      for (int tb = 0; tb < TB; tb++) {
        const char* sm = smem + tb*ABYTES;
#pragma unroll
        for (int mf = 0; mf < MF; mf++) {
          i32x4 a = *(const i32x4*)(sm + abase[mf] + base0);
          acc[tb][mf][0] = __builtin_amdgcn_mfma_i32_16x16x64_i8(a, c0, acc[tb][mf][0], 0, 0, 0);
          acc[tb][mf][1] = __builtin_amdgcn_mfma_i32_16x16x64_i8(a, c1, acc[tb][mf][1], 0, 0, 0);
          acc[tb][mf][2] = __builtin_amdgcn_mfma_i32_16x16x64_i8(a, c2, acc[tb][mf][2], 0, 0, 0);
          acc[tb][mf][3] = __builtin_amdgcn_mfma_i32_16x16x64_i8(a, c3, acc[tb][mf][3], 0, 0, 0);
        }
      }
      c0 = n0; c1 = n1; c2 = n2; c3 = n3;
      bo = bon;
    }

    // ---- epilogues per tb ----
#pragma unroll
    for (int tb = 0; tb < TB; tb++) {
      __syncthreads();
      float* cb = (float*)smem;
      unsigned char* zb = (unsigned char*)(smem + CBYTES);
      {
        int chn = wn*16 + (lane & 15);
#pragma unroll
        for (int mf = 0; mf < MF; mf++)
#pragma unroll
          for (int r = 0; r < 4; r++) {
            int pix = wm*MF*16 + mf*16 + kg*4 + r;
            double dv = (((double)acc[tb][mf][3][r]*256.0 + (double)acc[tb][mf][2][r])*256.0
                         + (double)acc[tb][mf][1][r])*256.0 + (double)acc[tb][mf][0][r];
            float cv = (float)(dv * (1.0/1073741824.0));
            cb[pix*BN + (chn ^ ((((unsigned)pix >> 2) & 3) << 2))] = cv;
          }
      }
      __syncthreads();
#pragma unroll
      for (int k = 0; k < ITER; k++) {
        int e = k*THREADS + tid;
        int row = e / R4;
        int ch  = (e % R4) * 4;
        f32x4 cv = *(const f32x4*)&cb[row*BN + (ch ^ ((((unsigned)row >> 2) & 3) << 2))];
        unsigned int zs[4];
#pragma unroll
        for (int s = 0; s < 4; s++) {
          float vdec = vreg[k][s] + DTM*((0.0f - vreg[k][s]) + ireg[k][s]);
          bool z = (vdec - VTH) > 0.0f;
          vreg[k][s] = z ? 0.0f : vdec;
          ireg[k][s] = SYN*ireg[k][s] + cv[s];
          zs[s] = z ? 1u : 0u;
        }
        *(unsigned int*)&zb[row*BN + ch] = zs[0] | (zs[1] << 8) | (zs[2] << 16) | (zs[3] << 24);
      }
      __syncthreads();
      unsigned char* zpool = zpool_all + (long)(t0 + tb)*ZDST_STEP;
      constexpr int WP = WI/2, PR = ROWS/2, CH16 = BN/16;
      for (int c = tid; c < PR*WP*CH16; c += THREADS) {
        int ppx = c / CH16, ck = c % CH16;
        int py = ppx / WP, px = ppx % WP;
        int b0_ = ((2*py)*WI + 2*px)*BN + ck*16;
        u32x4 q0 = *(const u32x4*)(zb + b0_);
        u32x4 q1 = *(const u32x4*)(zb + b0_ + BN);
        u32x4 q2 = *(const u32x4*)(zb + b0_ + WI*BN);
        u32x4 q3 = *(const u32x4*)(zb + b0_ + WI*BN + BN);
        u32x4 vo = (q0|q1)|(q2|q3);
        long g = ((long)(b*(HIM/2) + (y0>>1) + py)*WP + px)*COUT + nt*BN + ck*16;
        *(u32x4*)(zpool + g) = vo;
      }
    }
  }
}

// ---------------------------------------------------------------------------
// K5: FC(4096->10) over pooled i8 spikes + LI + noise + running max, all 16
// timesteps in-kernel, LI state in registers. 32 blocks x 512 threads.
// ---------------------------------------------------------------------------
__global__ __launch_bounds__(512) void k5_time(
    const unsigned char* __restrict__ z4p_all, const float* __restrict__ wfc,
    const float* __restrict__ noise, float* __restrict__ dout)
{
  __shared__ float red[8][10];
  int tid = threadIdx.x, b = blockIdx.x;
  float vo = 0.f, io = 0.f, mx = 0.f;

  for (int t = 0; t < 16; t++) {
    __syncthreads();
    const unsigned char* z4p = z4p_all + (long)t*131072;
    float sums[10];
#pragma unroll
    for (int j = 0; j < 10; j++) sums[j] = 0.f;
#pragma unroll
    for (int q = 0; q < 8; q++) {
      int k = q*512 + tid;
      int c = k >> 4, s = k & 15, py = s >> 2, px = s & 3;
      float zf = (float)z4p[((b*4 + py)*4 + px)*256 + c];
#pragma unroll
      for (int j = 0; j < 10; j++)
        sums[j] = fmaf(zf, wfc[j*4096 + k], sums[j]);
    }
#pragma unroll
    for (int j = 0; j < 10; j++) {
      float v = sums[j];
      for (int off = 32; off; off >>= 1) v += __shfl_xor(v, off);
      if ((tid & 63) == 0) red[tid >> 6][j] = v;
    }
    __syncthreads();
    if (tid < 10) {
      float o = 0.f;
#pragma unroll
      for (int w = 0; w < 8; w++) o += red[w][tid];
      float vn = vo + DTM*((0.0f - vo) + io);
      float inw = SYN*io + o;
      vo = vn; io = inw;
      float volt = vn + 0.001f*noise[((long)t*32 + b)*10 + tid];
      mx = (t == 0) ? volt : fmaxf(mx, volt);
    }
  }
  if (tid < 10) dout[b*10 + tid] = mx;
}

// ---------------------------------------------------------------------------
extern "C" void kernel_launch(void* const* d_in, const int* in_sizes, int n_in,
                              void* d_out, int out_size, void* d_ws, size_t ws_size,
                              hipStream_t stream)
{
  const float* x     = (const float*)d_in[0];
  const float* noise = (const float*)d_in[1];
  const float* w1    = (const float*)d_in[2];
  const float* w2    = (const float*)d_in[3];
  const float* w3    = (const float*)d_in[4];
  const float* w4    = (const float*)d_in[5];
  const float* wfc   = (const float*)d_in[6];
  float* dout = (float*)d_out;

  char* ws = (char*)d_ws;
  size_t off = 0;
  auto alloc = [&](size_t bytes) -> char* {
    char* p = ws + off;
    off = (off + bytes + 255) & ~(size_t)255;
    return p;
  };
  unsigned char* z1  = (unsigned char*)alloc(16u*2097152u);  // [16][32][32][32][64] i8
  unsigned char* z2p = (unsigned char*)alloc(16u*1048576u);  // [16][32][16][16][128] i8
  unsigned char* z3p = (unsigned char*)alloc(16u*524288u);   // [16][32][8][8][256] i8
  unsigned char* z4p = (unsigned char*)alloc(16u*131072u);   // [16][32][4][4][256] i8
  signed char* b2_0 = (signed char*)alloc(73728u);
  signed char* b2_1 = (signed char*)alloc(73728u);
  signed char* b2_2 = (signed char*)alloc(73728u);
  signed char* b2_3 = (signed char*)alloc(73728u);
  signed char* b3_0 = (signed char*)alloc(294912u);
  signed char* b3_1 = (signed char*)alloc(294912u);
  signed char* b3_2 = (signed char*)alloc(294912u);
  signed char* b3_3 = (signed char*)alloc(294912u);
  signed char* b4_0 = (signed char*)alloc(589824u);
  signed char* b4_1 = (signed char*)alloc(589824u);
  signed char* b4_2 = (signed char*)alloc(589824u);
  signed char* b4_3 = (signed char*)alloc(589824u);

  prep_kernel<<<3744, 256, 0, stream>>>(w2, w3, w4,
      b2_0, b2_1, b2_2, b2_3, b3_0, b3_1, b3_2, b3_3, b4_0, b4_1, b4_2, b4_3);

  // L1: conv1+LIF1, all t, grid 512
  k1_time<<<512, 256, 0, stream>>>(x, w1, z1);
  // L2: 64->128 @32x32. WM2xWN2, MF2 (BM=64,BN=32), TB2, NT=4, grid 2048
  conv_time<2,2,2,2,2,  64,32,32,128,4, 2097152,1048576><<<2048, 256, 0, stream>>>(
      z1, b2_0, b2_1, b2_2, b2_3, z2p);
  // L3: 128->256 @16x16. WM2xWN2, MF1 (BM=32,BN=32), TB2, NT=8, grid 2048
  conv_time<2,2,1,2,3, 128,16,16,256,8, 1048576, 524288><<<2048, 256, 0, stream>>>(
      z2p, b3_0, b3_1, b3_2, b3_3, z3p);
  // L4: 256->256 @8x8, full K=256 in-block (i32 exact). WM2xWN2, MF1, TB2,
  // NT=8, grid 512
  conv_time<2,2,1,2,3, 256, 8, 8,256,8,  524288, 131072><<<512, 256, 0, stream>>>(
      z3p, b4_0, b4_1, b4_2, b4_3, z4p);
  // FC + LI + max, all t, grid 32
  k5_time<<<32, 512, 0, stream>>>(z4p, wfc, noise, dout);
}